// Round 15
// baseline (300.660 us; speedup 1.0000x reference)
//
#include <hip/hip_runtime.h>
#include <math.h>

// ---------------------------------------------------------------------------
// TGN GraphAttentionEmbedding, MFMA bf16, dst-sorted dataflow (7 launches):
//   memset -> k_front(prep+hist) -> k_bsum -> k_scan2(inline bscan) ->
//   k_scatter -> k_heavy(egemm || node) -> k_agg
// ---------------------------------------------------------------------------

typedef __attribute__((ext_vector_type(8))) short bf16x8;
typedef __attribute__((ext_vector_type(4))) float f32x4;

__device__ inline short f2bf(float f) {
  unsigned u = __float_as_uint(f);
  u += 0x7fff + ((u >> 16) & 1);     // round-to-nearest-even
  return (short)(u >> 16);
}
__device__ inline float bflo(unsigned u) { return __uint_as_float(u << 16); }
__device__ inline float bfhi(unsigned u) { return __uint_as_float(u & 0xffff0000u); }

// ---- front: W shuffle into MFMA B-frag layout (blocks 0-39) + dst hist ----
struct PrepArgs { const float* W[5]; };
__global__ void k_front(PrepArgs pa, short* __restrict__ wf,
                        const int* __restrict__ ei, int* __restrict__ counts,
                        int E) {
  const int b = blockIdx.x;
  if (b < 40) {
    int tid = b * 256 + threadIdx.x;
    if (tid >= 5 * 8 * 4 * 64) return;
    int lane = tid & 63;
    int kt = (tid >> 6) & 3;
    int nt = (tid >> 8) & 7;
    int mat = tid >> 11;
    const float* W = pa.W[mat];
    int n = nt * 16 + (lane & 15);
    short v[8];
#pragma unroll
    for (int j = 0; j < 8; ++j) {
      int k = kt * 32 + ((j >> 2) * 16) + ((lane >> 4) * 4) + (j & 3);
      v[j] = f2bf(W[k * 128 + n]);
    }
    ((uint4*)wf)[tid] = *(uint4*)v;
  } else {
    int i = (b - 40) * 256 + threadIdx.x;
    if (i < E) atomicAdd(&counts[ei[E + i]], 1);
  }
}

__global__ __launch_bounds__(1024) void k_bsum(const int* __restrict__ counts,
                                               int* __restrict__ bsum, int N) {
  int i = blockIdx.x * 1024 + threadIdx.x;
  int v = (i < N) ? counts[i] : 0;
  for (int d = 32; d; d >>= 1) v += __shfl_down(v, d);
  __shared__ int ws_[16];
  int lane = threadIdx.x & 63, wv = threadIdx.x >> 6;
  if (lane == 0) ws_[wv] = v;
  __syncthreads();
  if (threadIdx.x == 0) {
    int s = 0;
    for (int j = 0; j < 16; ++j) s += ws_[j];
    bsum[blockIdx.x] = s;
  }
}

// scan2 with INLINE prefix-of-bsum (replaces k_bscan)
__global__ __launch_bounds__(1024) void k_scan2(const int* __restrict__ counts,
                                                const int* __restrict__ bsum,
                                                int* __restrict__ offs,
                                                int* __restrict__ cursor,
                                                int N, int nb) {
  __shared__ int sh[1024];
  __shared__ int wsum[16];
  const int t = threadIdx.x;
  const int b = blockIdx.x;
  // block prefix: sum of bsum[0..b)  (b <= nb-1 <= 97 < 1024)
  int pv = (t < b && t < nb) ? bsum[t] : 0;
  for (int d = 32; d; d >>= 1) pv += __shfl_down(pv, d);
  if ((t & 63) == 0) wsum[t >> 6] = pv;
  __syncthreads();
  if (t == 0) {
    int s = 0;
    for (int j = 0; j < 16; ++j) s += wsum[j];
    wsum[0] = s;
  }
  __syncthreads();
  const int bpre = wsum[0];

  int i = b * 1024 + t;
  int v = (i < N) ? counts[i] : 0;
  sh[t] = v;
  __syncthreads();
  for (int d = 1; d < 1024; d <<= 1) {
    int u = (t >= d) ? sh[t - d] : 0;
    __syncthreads();
    sh[t] += u;
    __syncthreads();
  }
  if (i < N) {
    int excl = bpre + sh[t] - v;
    offs[i] = excl;
    cursor[i] = excl;
    if (i == N - 1) offs[N] = excl + v;
  }
}

// rank[i]: sorted position of original edge i; src_s[pos]: src of that edge
__global__ void k_scatter(const int* __restrict__ ei, int* __restrict__ cursor,
                          int* __restrict__ rank, int* __restrict__ src_s, int E) {
  int i = blockIdx.x * 256 + threadIdx.x;
  if (i < E) {
    int pos = atomicAdd(&cursor[ei[E + i]], 1);
    rank[i] = pos;
    src_s[pos] = ei[i];
  }
}

// ---- heavy: edge GEMM (blocks r<2 of each 5) || node GEMMs (r>=2) ---------
struct HeavyArgs {
  const short* wf;
  const float* bias[4];
  void* outp[4];
  const float* lu;
  const int* ei;
  const float* t;
  const float* msg;
  const float* tw;
  const float* tb;
  const int* rank;
  short* e_s;
};

__global__ __launch_bounds__(256, 2) void k_heavy(
    const float* __restrict__ x, const float* __restrict__ feats,
    HeavyArgs ha, int N, int E, int negemm, int nnode) {
  __shared__ char smem[49152];
  const int lane = threadIdx.x & 63;
  const int wv = threadIdx.x >> 6;
  const int g = blockIdx.x / 5, r5 = blockIdx.x % 5;

  if (r5 < 2) {
    // ---------------- edge GEMM branch ----------------
    const int eb = g * 2 + r5;
    if (eb >= negemm) return;
    uint4* wlds = (uint4*)smem;                 // 32 KB We fragment
    char* myl = smem + 32768 + wv * 4096;       // per-wave transpose slice
    for (int i = threadIdx.x; i < 2048; i += 256)
      wlds[i] = ((const uint4*)ha.wf)[8192 + i];   // mat 4 = We
    __syncthreads();

    const int k4 = (lane >> 4) * 4;
    float twv[16], tbv[16];
#pragma unroll
    for (int kt = 0; kt < 2; ++kt) {
      int base = kt * 32 + k4;
      *(float4*)&twv[kt * 8]     = *(const float4*)(ha.tw + base);
      *(float4*)&twv[kt * 8 + 4] = *(const float4*)(ha.tw + base + 16);
      *(float4*)&tbv[kt * 8]     = *(const float4*)(ha.tb + base);
      *(float4*)&tbv[kt * 8 + 4] = *(const float4*)(ha.tb + base + 16);
    }

    const int ntiles = (E + 15) / 16;
    const int nwaves = negemm * 4;
    int tile = eb * 4 + wv;
    int p_src = 0, p_rank = 0;
    float p_t = 0.f;
    if (tile < ntiles && lane < 16 && tile * 16 + lane < E) {
      p_src  = ha.ei[tile * 16 + lane];
      p_rank = ha.rank[tile * 16 + lane];
      p_t    = ha.t[tile * 16 + lane];
    }
    for (; tile < ntiles; tile += nwaves) {
      const int e0 = tile * 16;
      const int rank16 = p_rank;
      float relt = 0.f;
      if (lane < 16 && e0 + lane < E)
        relt = ha.lu[p_src] - p_t;
      const int ntile = tile + nwaves;
      if (ntile < ntiles && lane < 16 && ntile * 16 + lane < E) {
        p_src  = ha.ei[ntile * 16 + lane];
        p_rank = ha.rank[ntile * 16 + lane];
        p_t    = ha.t[ntile * 16 + lane];
      }
      const int r = lane & 15;
      float my_relt = __shfl(relt, r);
      bool rvalid = (e0 + r) < E;

      bf16x8 afrag[4];
#pragma unroll
      for (int kt = 0; kt < 2; ++kt) {
        bf16x8 a;
#pragma unroll
        for (int j = 0; j < 8; ++j)
          a[j] = f2bf(__cosf(my_relt * twv[kt * 8 + j] + tbv[kt * 8 + j]));
        afrag[kt] = a;
      }
      const float* mr = ha.msg + (size_t)(e0 + r) * 64;
#pragma unroll
      for (int kt = 2; kt < 4; ++kt) {
        int base = (kt - 2) * 32 + k4;
        float4 lo = rvalid ? *(const float4*)(mr + base) : make_float4(0, 0, 0, 0);
        float4 hi = rvalid ? *(const float4*)(mr + base + 16) : make_float4(0, 0, 0, 0);
        bf16x8 a;
        a[0] = f2bf(lo.x); a[1] = f2bf(lo.y); a[2] = f2bf(lo.z); a[3] = f2bf(lo.w);
        a[4] = f2bf(hi.x); a[5] = f2bf(hi.y); a[6] = f2bf(hi.z); a[7] = f2bf(hi.w);
        afrag[kt] = a;
      }

#pragma unroll
      for (int nt = 0; nt < 8; ++nt) {
        bf16x8 bfrag[4];
#pragma unroll
        for (int kt = 0; kt < 4; ++kt)
          *(uint4*)&bfrag[kt] = wlds[(nt * 4 + kt) * 64 + lane];
        f32x4 acc = {0.f, 0.f, 0.f, 0.f};
#pragma unroll
        for (int kt = 0; kt < 4; ++kt)
          acc = __builtin_amdgcn_mfma_f32_16x16x32_bf16(afrag[kt], bfrag[kt], acc, 0, 0, 0);
        int col = nt * 16 + (lane & 15);
#pragma unroll
        for (int reg = 0; reg < 4; ++reg) {
          int rr = (lane >> 4) * 4 + reg;
          int wb = (rr * 256 + col * 2) ^ (((rr >> 2) & 3) << 5);
          *(short*)(myl + wb) = f2bf(acc[reg]);
        }
      }
#pragma unroll
      for (int i = 0; i < 8; ++i) {
        int rr = i * 2 + (lane >> 5);
        int er = e0 + rr;
        int drow = __shfl(rank16, rr);
        int rb = (rr * 256 + (lane & 31) * 8) ^ (((rr >> 2) & 3) << 5);
        uint2 val = *(const uint2*)(myl + rb);
        if (er < E)
          *(uint2*)(ha.e_s + (size_t)drow * 128 + (lane & 31) * 4) = val;
      }
    }
  } else {
    // ---------------- node GEMM branch ----------------
    const int nb2 = g * 3 + (r5 - 2);
    if (nb2 >= nnode) return;
    char* myl = smem + wv * 8192;

    bf16x8 bfrag[8][4];
    const uint4* wfp = (const uint4*)ha.wf + (size_t)wv * 2048;
#pragma unroll
    for (int nt = 0; nt < 8; ++nt)
#pragma unroll
      for (int kt = 0; kt < 4; ++kt)
        *(uint4*)&bfrag[nt][kt] = wfp[(nt * 4 + kt) * 64 + lane];

    float biasv[8];
#pragma unroll
    for (int nt = 0; nt < 8; ++nt)
      biasv[nt] = ha.bias[wv][nt * 16 + (lane & 15)];
    void* op = ha.outp[wv];

    const int arow = lane & 15;
    const int k4 = (lane >> 4) * 4;
    const int ntiles = (N + 15) / 16;
    for (int tile = nb2; tile < ntiles; tile += nnode) {
      int row = tile * 16 + arow;
      bool valid = row < N;
      const float* xr = x + (size_t)row * 64;
      const float* fr = feats + (size_t)row * 64;
      bf16x8 afrag[4];
#pragma unroll
      for (int kt = 0; kt < 4; ++kt) {
        const float* src = (kt < 2) ? xr : fr;
        int base = (kt & 1) * 32 + k4;
        float4 lo = valid ? *(const float4*)(src + base) : make_float4(0, 0, 0, 0);
        float4 hi = valid ? *(const float4*)(src + base + 16) : make_float4(0, 0, 0, 0);
        bf16x8 a;
        a[0] = f2bf(lo.x); a[1] = f2bf(lo.y); a[2] = f2bf(lo.z); a[3] = f2bf(lo.w);
        a[4] = f2bf(hi.x); a[5] = f2bf(hi.y); a[6] = f2bf(hi.z); a[7] = f2bf(hi.w);
        afrag[kt] = a;
      }
#pragma unroll
      for (int nt = 0; nt < 8; ++nt) {
        f32x4 acc = {0.f, 0.f, 0.f, 0.f};
#pragma unroll
        for (int kt = 0; kt < 4; ++kt)
          acc = __builtin_amdgcn_mfma_f32_16x16x32_bf16(afrag[kt], bfrag[nt][kt], acc, 0, 0, 0);
        int col = nt * 16 + (lane & 15);
#pragma unroll
        for (int reg = 0; reg < 4; ++reg) {
          int r = (lane >> 4) * 4 + reg;
          float vv = acc[reg] + biasv[nt];
          if (wv < 3) {
            int wb = (r * 256 + col * 2) ^ (((r >> 2) & 3) << 5);
            *(short*)(myl + wb) = f2bf(vv);
          } else {
            int wb = (r * 512 + col * 4) ^ (((r >> 2) & 3) << 6);
            *(float*)(myl + wb) = vv;
          }
        }
      }
      if (wv < 3) {
        short* opp = (short*)op;
#pragma unroll
        for (int i = 0; i < 8; ++i) {
          int r = i * 2 + (lane >> 5);
          int orow = tile * 16 + r;
          int rb = (r * 256 + (lane & 31) * 8) ^ (((r >> 2) & 3) << 5);
          uint2 val = *(const uint2*)(myl + rb);
          if (orow < N)
            *(uint2*)(opp + (size_t)orow * 128 + (lane & 31) * 4) = val;
        }
      } else {
        float* opp = (float*)op;
#pragma unroll
        for (int i = 0; i < 8; ++i) {
          int r = i * 2 + (lane >> 5);
          int orow = tile * 16 + r;
          int rb = (r * 512 + (lane & 31) * 16) ^ (((r >> 2) & 3) << 6);
          uint4 val = *(const uint4*)(myl + rb);
          if (orow < N)
            *(uint4*)(opp + (size_t)orow * 128 + (lane & 31) * 4) = val;
        }
      }
    }
  }
}

// ---- per-dst aggregation: round-12 measured-best form ---------------------
__global__ __launch_bounds__(256) void k_agg(
    const int* __restrict__ offs, const int* __restrict__ src_s,
    const short* __restrict__ e_s, const short* __restrict__ qb,
    const short* __restrict__ kb, const short* __restrict__ vb,
    float* __restrict__ out, int N) {
  __shared__ int lds_vo[4][64];
  const int wave = threadIdx.x >> 6;
  const int lane = threadIdx.x & 63;
  const int n0 = (blockIdx.x * 4 + wave) * 2;
  if (n0 >= N) return;
  const int c2 = lane * 2;
  const bool hasB = (n0 + 1) < N;

  const int offA = offs[n0];
  const int endA = offs[n0 + 1];
  const int endB = hasB ? offs[n0 + 2] : endA;
  const int offB = endA;
  unsigned qvA = *(const unsigned*)(qb + (size_t)n0 * 128 + c2);
  unsigned qvB = hasB ? *(const unsigned*)(qb + (size_t)(n0 + 1) * 128 + c2) : 0u;
  float2 oA = *(float2*)(out + (size_t)n0 * 128 + c2);
  float2 oB = hasB ? *(float2*)(out + (size_t)(n0 + 1) * 128 + c2)
                   : make_float2(0.f, 0.f);

  auto process = [&](int off, int end, unsigned qv, float2& o) {
    if (end <= off) return;               // out keeps skip value
    const float q0 = bflo(qv), q1 = bfhi(qv);
    float s = 0.f, acc0 = 0.f, acc1 = 0.f;
    for (int c0 = off; c0 < end; c0 += 64) {
      const int cnt = min(64, end - c0);
      if (lane < cnt) lds_vo[wave][lane] = src_s[c0 + lane] * 128;
      const int lim = cnt - 1;
      for (int g0 = 0; g0 < cnt; g0 += 8) {
        unsigned evr[8], kvr[8], vvr[8];
#pragma unroll
        for (int g = 0; g < 8; ++g) {
          int jj = g0 + g;
          jj = (jj > lim) ? lim : jj;     // clamp: always a valid edge
          int vo = lds_vo[wave][jj];
          evr[g] = *(const unsigned*)(e_s + (size_t)(c0 + jj) * 128 + c2);
          kvr[g] = *(const unsigned*)(kb + vo + c2);
          vvr[g] = *(const unsigned*)(vb + vo + c2);
        }
#pragma unroll
        for (int g = 0; g < 8; ++g) {
          float part = q0 * (bflo(kvr[g]) + bflo(evr[g]))
                     + q1 * (bfhi(kvr[g]) + bfhi(evr[g]));
          part += __shfl_xor(part, 1);
          part += __shfl_xor(part, 2);
          part += __shfl_xor(part, 4);    // sum over the 8-lane head group
          float p = (g0 + g <= lim) ? __expf(part * 0.25f) : 0.f;
          s += p;
          acc0 = fmaf(p, bflo(vvr[g]) + bflo(evr[g]), acc0);
          acc1 = fmaf(p, bfhi(vvr[g]) + bfhi(evr[g]), acc1);
        }
      }
    }
    float r = 1.f / (s + 1e-16f);
    o.x += acc0 * r;
    o.y += acc1 * r;
  };

  process(offA, endA, qvA, oA);
  *(float2*)(out + (size_t)n0 * 128 + c2) = oA;
  if (hasB) {
    process(offB, endB, qvB, oB);
    *(float2*)(out + (size_t)(n0 + 1) * 128 + c2) = oB;
  }
}

extern "C" void kernel_launch(void* const* d_in, const int* in_sizes, int n_in,
                              void* d_out, int out_size, void* d_ws, size_t ws_size,
                              hipStream_t stream) {
  const float* feats = (const float*)d_in[0];
  const float* x     = (const float*)d_in[1];
  const float* lu    = (const float*)d_in[2];
  const int*   ei    = (const int*)d_in[3];
  const float* t     = (const float*)d_in[4];
  const float* msg   = (const float*)d_in[5];
  const float* tw    = (const float*)d_in[6];
  const float* tb    = (const float*)d_in[7];
  const float* Wq    = (const float*)d_in[8];
  const float* bq    = (const float*)d_in[9];
  const float* Wk    = (const float*)d_in[10];
  const float* bk    = (const float*)d_in[11];
  const float* Wv    = (const float*)d_in[12];
  const float* bv    = (const float*)d_in[13];
  const float* We    = (const float*)d_in[14];
  const float* Wskip = (const float*)d_in[15];
  const float* bskip = (const float*)d_in[16];
  float* out = (float*)d_out;
  const int N = in_sizes[2];
  const int E = in_sizes[4];

  char* ws = (char*)d_ws;
  short* wfrag = (short*)ws; ws += 5 * 2048 * 16;            // 160 KB
  short* qb    = (short*)ws; ws += (size_t)N * 128 * 2;
  short* kbuf  = (short*)ws; ws += (size_t)N * 128 * 2;
  short* vbuf  = (short*)ws; ws += (size_t)N * 128 * 2;
  short* e_s   = (short*)ws; ws += (size_t)E * 128 * 2;
  int* counts  = (int*)ws;   ws += (size_t)(N + 1) * 4;
  int* offs    = (int*)ws;   ws += (size_t)(N + 4) * 4;
  int* cursor  = (int*)ws;   ws += (size_t)N * 4;
  int* rank    = (int*)ws;   ws += (size_t)E * 4;
  int* src_s   = (int*)ws;   ws += (size_t)E * 4;
  int* bsum    = (int*)ws;   ws += 128 * 4;

  const int nb = (N + 1023) / 1024;
  const int nhist = (E + 255) / 256;

  hipMemsetAsync(counts, 0, (size_t)(N + 1) * 4, stream);

  PrepArgs pa;
  pa.W[0] = Wq; pa.W[1] = Wk; pa.W[2] = Wv; pa.W[3] = Wskip; pa.W[4] = We;
  k_front<<<40 + nhist, 256, 0, stream>>>(pa, wfrag, ei, counts, E);

  k_bsum<<<nb, 1024, 0, stream>>>(counts, bsum, N);
  k_scan2<<<nb, 1024, 0, stream>>>(counts, bsum, offs, cursor, N, nb);
  k_scatter<<<nhist, 256, 0, stream>>>(ei, cursor, rank, src_s, E);

  HeavyArgs ha;
  ha.wf = wfrag;
  ha.bias[0] = bq; ha.bias[1] = bk; ha.bias[2] = bv; ha.bias[3] = bskip;
  ha.outp[0] = qb; ha.outp[1] = kbuf; ha.outp[2] = vbuf; ha.outp[3] = out;
  ha.lu = lu; ha.ei = ei; ha.t = t; ha.msg = msg;
  ha.tw = tw; ha.tb = tb; ha.rank = rank; ha.e_s = e_s;
  const int negemm = 512, nnode = 768;   // interleaved 2:3 per 5 blocks
  k_heavy<<<5 * 256, 256, 0, stream>>>(x, feats, ha, N, E, negemm, nnode);

  k_agg<<<(N + 7) / 8, 256, 0, stream>>>(offs, src_s, e_s, qb, kbuf, vbuf,
                                         out, N);
}

// Round 16
// 275.753 us; speedup vs baseline: 1.0903x; 1.0903x over previous
//
#include <hip/hip_runtime.h>
#include <math.h>

// ---------------------------------------------------------------------------
// TGN GraphAttentionEmbedding, MFMA bf16, dst-sorted dataflow (8 launches):
//   memset -> k_front(prep+hist) -> k_bsum -> k_scan2(inline bscan) ->
//   k_scatter -> k_node -> k_egemm -> k_agg
// Best-of consolidation: r13 node/egemm, r12 agg, r15 front/scan fusions.
// ---------------------------------------------------------------------------

typedef __attribute__((ext_vector_type(8))) short bf16x8;
typedef __attribute__((ext_vector_type(4))) float f32x4;

__device__ inline short f2bf(float f) {
  unsigned u = __float_as_uint(f);
  u += 0x7fff + ((u >> 16) & 1);     // round-to-nearest-even
  return (short)(u >> 16);
}
__device__ inline float bflo(unsigned u) { return __uint_as_float(u << 16); }
__device__ inline float bfhi(unsigned u) { return __uint_as_float(u & 0xffff0000u); }

// ---- front: W shuffle into MFMA B-frag layout (blocks 0-39) + dst hist ----
struct PrepArgs { const float* W[5]; };
__global__ void k_front(PrepArgs pa, short* __restrict__ wf,
                        const int* __restrict__ ei, int* __restrict__ counts,
                        int E) {
  const int b = blockIdx.x;
  if (b < 40) {
    int tid = b * 256 + threadIdx.x;
    if (tid >= 5 * 8 * 4 * 64) return;
    int lane = tid & 63;
    int kt = (tid >> 6) & 3;
    int nt = (tid >> 8) & 7;
    int mat = tid >> 11;
    const float* W = pa.W[mat];
    int n = nt * 16 + (lane & 15);
    short v[8];
#pragma unroll
    for (int j = 0; j < 8; ++j) {
      int k = kt * 32 + ((j >> 2) * 16) + ((lane >> 4) * 4) + (j & 3);
      v[j] = f2bf(W[k * 128 + n]);
    }
    ((uint4*)wf)[tid] = *(uint4*)v;
  } else {
    int i = (b - 40) * 256 + threadIdx.x;
    if (i < E) atomicAdd(&counts[ei[E + i]], 1);
  }
}

__global__ __launch_bounds__(1024) void k_bsum(const int* __restrict__ counts,
                                               int* __restrict__ bsum, int N) {
  int i = blockIdx.x * 1024 + threadIdx.x;
  int v = (i < N) ? counts[i] : 0;
  for (int d = 32; d; d >>= 1) v += __shfl_down(v, d);
  __shared__ int ws_[16];
  int lane = threadIdx.x & 63, wv = threadIdx.x >> 6;
  if (lane == 0) ws_[wv] = v;
  __syncthreads();
  if (threadIdx.x == 0) {
    int s = 0;
    for (int j = 0; j < 16; ++j) s += ws_[j];
    bsum[blockIdx.x] = s;
  }
}

// scan2 with INLINE prefix-of-bsum (replaces k_bscan)
__global__ __launch_bounds__(1024) void k_scan2(const int* __restrict__ counts,
                                                const int* __restrict__ bsum,
                                                int* __restrict__ offs,
                                                int* __restrict__ cursor,
                                                int N, int nb) {
  __shared__ int sh[1024];
  __shared__ int wsum[16];
  const int t = threadIdx.x;
  const int b = blockIdx.x;
  int pv = (t < b && t < nb) ? bsum[t] : 0;
  for (int d = 32; d; d >>= 1) pv += __shfl_down(pv, d);
  if ((t & 63) == 0) wsum[t >> 6] = pv;
  __syncthreads();
  if (t == 0) {
    int s = 0;
    for (int j = 0; j < 16; ++j) s += wsum[j];
    wsum[0] = s;
  }
  __syncthreads();
  const int bpre = wsum[0];

  int i = b * 1024 + t;
  int v = (i < N) ? counts[i] : 0;
  sh[t] = v;
  __syncthreads();
  for (int d = 1; d < 1024; d <<= 1) {
    int u = (t >= d) ? sh[t - d] : 0;
    __syncthreads();
    sh[t] += u;
    __syncthreads();
  }
  if (i < N) {
    int excl = bpre + sh[t] - v;
    offs[i] = excl;
    cursor[i] = excl;
    if (i == N - 1) offs[N] = excl + v;
  }
}

// rank[i]: sorted position of original edge i; src_s[pos]: src of that edge
__global__ void k_scatter(const int* __restrict__ ei, int* __restrict__ cursor,
                          int* __restrict__ rank, int* __restrict__ src_s, int E) {
  int i = blockIdx.x * 256 + threadIdx.x;
  if (i < E) {
    int pos = atomicAdd(&cursor[ei[E + i]], 1);
    rank[i] = pos;
    src_s[pos] = ei[i];
  }
}

// ---- node GEMMs: wave wv owns matrix wv (B-frag persistent in VGPRs) ------
struct NodeArgs {
  const short* wf;
  const float* bias[4];
  void* outp[4];
};

__global__ __launch_bounds__(256, 2) void k_node(
    const float* __restrict__ x, const float* __restrict__ feats,
    NodeArgs na, int N) {
  __shared__ char lds[4][8192];           // per-wave transpose slice
  const int lane = threadIdx.x & 63;
  const int wv = threadIdx.x >> 6;        // matrix index: 0=q 1=k 2=v 3=skip
  char* myl = lds[wv];

  bf16x8 bfrag[8][4];
  const uint4* wfp = (const uint4*)na.wf + (size_t)wv * 2048;
#pragma unroll
  for (int nt = 0; nt < 8; ++nt)
#pragma unroll
    for (int kt = 0; kt < 4; ++kt)
      *(uint4*)&bfrag[nt][kt] = wfp[(nt * 4 + kt) * 64 + lane];

  float biasv[8];
#pragma unroll
  for (int nt = 0; nt < 8; ++nt) biasv[nt] = na.bias[wv][nt * 16 + (lane & 15)];
  void* op = na.outp[wv];

  const int arow = lane & 15;
  const int k4 = (lane >> 4) * 4;
  const int ntiles = (N + 15) / 16;
  for (int tile = blockIdx.x; tile < ntiles; tile += gridDim.x) {
    int row = tile * 16 + arow;
    bool valid = row < N;
    const float* xr = x + (size_t)row * 64;
    const float* fr = feats + (size_t)row * 64;
    bf16x8 afrag[4];
#pragma unroll
    for (int kt = 0; kt < 4; ++kt) {
      const float* src = (kt < 2) ? xr : fr;
      int base = (kt & 1) * 32 + k4;
      float4 lo = valid ? *(const float4*)(src + base) : make_float4(0, 0, 0, 0);
      float4 hi = valid ? *(const float4*)(src + base + 16) : make_float4(0, 0, 0, 0);
      bf16x8 a;
      a[0] = f2bf(lo.x); a[1] = f2bf(lo.y); a[2] = f2bf(lo.z); a[3] = f2bf(lo.w);
      a[4] = f2bf(hi.x); a[5] = f2bf(hi.y); a[6] = f2bf(hi.z); a[7] = f2bf(hi.w);
      afrag[kt] = a;
    }
#pragma unroll
    for (int nt = 0; nt < 8; ++nt) {
      f32x4 acc = {0.f, 0.f, 0.f, 0.f};
#pragma unroll
      for (int kt = 0; kt < 4; ++kt)
        acc = __builtin_amdgcn_mfma_f32_16x16x32_bf16(afrag[kt], bfrag[nt][kt], acc, 0, 0, 0);
      int col = nt * 16 + (lane & 15);
#pragma unroll
      for (int reg = 0; reg < 4; ++reg) {
        int r = (lane >> 4) * 4 + reg;
        float vv = acc[reg] + biasv[nt];
        if (wv < 3) {
          int wb = (r * 256 + col * 2) ^ (((r >> 2) & 3) << 5);  // swizzled
          *(short*)(myl + wb) = f2bf(vv);
        } else {
          int wb = (r * 512 + col * 4) ^ (((r >> 2) & 3) << 6);  // swizzled
          *(float*)(myl + wb) = vv;
        }
      }
    }
    if (wv < 3) {
      short* opp = (short*)op;
#pragma unroll
      for (int i = 0; i < 8; ++i) {
        int r = i * 2 + (lane >> 5);
        int orow = tile * 16 + r;
        int rb = (r * 256 + (lane & 31) * 8) ^ (((r >> 2) & 3) << 5);
        uint2 val = *(const uint2*)(myl + rb);
        if (orow < N)
          *(uint2*)(opp + (size_t)orow * 128 + (lane & 31) * 4) = val;
      }
    } else {
      float* opp = (float*)op;
#pragma unroll
      for (int i = 0; i < 8; ++i) {
        int r = i * 2 + (lane >> 5);
        int orow = tile * 16 + r;
        int rb = (r * 512 + (lane & 31) * 16) ^ (((r >> 2) & 3) << 6);
        uint4 val = *(const uint4*)(myl + rb);
        if (orow < N)
          *(uint4*)(opp + (size_t)orow * 128 + (lane & 31) * 4) = val;
      }
    }
  }
}

// ---- edge GEMM, orig order, LDS-staged We-frag, index prefetch ------------
__global__ __launch_bounds__(512) void k_egemm(
    const float* __restrict__ lu, const int* __restrict__ ei,
    const float* __restrict__ t, const float* __restrict__ msg,
    const float* __restrict__ tw, const float* __restrict__ tb,
    const short* __restrict__ wf, const int* __restrict__ rank,
    short* __restrict__ e_s, int E) {
  __shared__ uint4 wlds[2048];            // 32 KB We fragment, block-shared
  __shared__ char tbuf[8][4096];          // per-wave 16x128 bf16 transpose
  const int lane = threadIdx.x & 63;
  const int wv = threadIdx.x >> 6;
  char* myl = tbuf[wv];

  for (int i = threadIdx.x; i < 2048; i += 512)
    wlds[i] = ((const uint4*)wf)[8192 + i];     // mat 4 = We
  __syncthreads();

  const int k4 = (lane >> 4) * 4;
  float twv[16], tbv[16];
#pragma unroll
  for (int kt = 0; kt < 2; ++kt) {
    int base = kt * 32 + k4;
    *(float4*)&twv[kt * 8]     = *(const float4*)(tw + base);
    *(float4*)&twv[kt * 8 + 4] = *(const float4*)(tw + base + 16);
    *(float4*)&tbv[kt * 8]     = *(const float4*)(tb + base);
    *(float4*)&tbv[kt * 8 + 4] = *(const float4*)(tb + base + 16);
  }

  const int ntiles = (E + 15) / 16;
  const int nwaves = gridDim.x * 8;
  int tile = blockIdx.x * 8 + wv;
  int p_src = 0, p_rank = 0;
  float p_t = 0.f;
  if (tile < ntiles && lane < 16 && tile * 16 + lane < E) {
    p_src  = ei[tile * 16 + lane];
    p_rank = rank[tile * 16 + lane];
    p_t    = t[tile * 16 + lane];
  }
  for (; tile < ntiles; tile += nwaves) {
    const int e0 = tile * 16;
    const int rank16 = p_rank;
    float relt = 0.f;
    if (lane < 16 && e0 + lane < E)
      relt = lu[p_src] - p_t;             // lu: 400KB L2-resident gather
    const int ntile = tile + nwaves;
    if (ntile < ntiles && lane < 16 && ntile * 16 + lane < E) {
      p_src  = ei[ntile * 16 + lane];
      p_rank = rank[ntile * 16 + lane];
      p_t    = t[ntile * 16 + lane];
    }
    const int r = lane & 15;
    float my_relt = __shfl(relt, r);
    bool rvalid = (e0 + r) < E;

    bf16x8 afrag[4];
#pragma unroll
    for (int kt = 0; kt < 2; ++kt) {
      bf16x8 a;
#pragma unroll
      for (int j = 0; j < 8; ++j)
        a[j] = f2bf(__cosf(my_relt * twv[kt * 8 + j] + tbv[kt * 8 + j]));
      afrag[kt] = a;
    }
    const float* mr = msg + (size_t)(e0 + r) * 64;   // streaming, coalesced
#pragma unroll
    for (int kt = 2; kt < 4; ++kt) {
      int base = (kt - 2) * 32 + k4;
      float4 lo = rvalid ? *(const float4*)(mr + base) : make_float4(0, 0, 0, 0);
      float4 hi = rvalid ? *(const float4*)(mr + base + 16) : make_float4(0, 0, 0, 0);
      bf16x8 a;
      a[0] = f2bf(lo.x); a[1] = f2bf(lo.y); a[2] = f2bf(lo.z); a[3] = f2bf(lo.w);
      a[4] = f2bf(hi.x); a[5] = f2bf(hi.y); a[6] = f2bf(hi.z); a[7] = f2bf(hi.w);
      afrag[kt] = a;
    }

#pragma unroll
    for (int nt = 0; nt < 8; ++nt) {
      bf16x8 bfrag[4];
#pragma unroll
      for (int kt = 0; kt < 4; ++kt)
        *(uint4*)&bfrag[kt] = wlds[(nt * 4 + kt) * 64 + lane];
      f32x4 acc = {0.f, 0.f, 0.f, 0.f};
#pragma unroll
      for (int kt = 0; kt < 4; ++kt)
        acc = __builtin_amdgcn_mfma_f32_16x16x32_bf16(afrag[kt], bfrag[kt], acc, 0, 0, 0);
      int col = nt * 16 + (lane & 15);
#pragma unroll
      for (int reg = 0; reg < 4; ++reg) {
        int rr = (lane >> 4) * 4 + reg;
        int wb = (rr * 256 + col * 2) ^ (((rr >> 2) & 3) << 5);  // swizzled
        *(short*)(myl + wb) = f2bf(acc[reg]);
      }
    }
#pragma unroll
    for (int i = 0; i < 8; ++i) {
      int rr = i * 2 + (lane >> 5);
      int er = e0 + rr;
      int drow = __shfl(rank16, rr);        // sorted row for this edge
      int rb = (rr * 256 + (lane & 31) * 8) ^ (((rr >> 2) & 3) << 5);
      uint2 val = *(const uint2*)(myl + rb);
      if (er < E)
        *(uint2*)(e_s + (size_t)drow * 128 + (lane & 31) * 4) = val;
    }
  }
}

// ---- per-dst aggregation: round-12 measured-best form ---------------------
__global__ __launch_bounds__(256) void k_agg(
    const int* __restrict__ offs, const int* __restrict__ src_s,
    const short* __restrict__ e_s, const short* __restrict__ qb,
    const short* __restrict__ kb, const short* __restrict__ vb,
    float* __restrict__ out, int N) {
  __shared__ int lds_vo[4][64];
  const int wave = threadIdx.x >> 6;
  const int lane = threadIdx.x & 63;
  const int n0 = (blockIdx.x * 4 + wave) * 2;
  if (n0 >= N) return;
  const int c2 = lane * 2;
  const bool hasB = (n0 + 1) < N;

  const int offA = offs[n0];
  const int endA = offs[n0 + 1];
  const int endB = hasB ? offs[n0 + 2] : endA;
  const int offB = endA;
  unsigned qvA = *(const unsigned*)(qb + (size_t)n0 * 128 + c2);
  unsigned qvB = hasB ? *(const unsigned*)(qb + (size_t)(n0 + 1) * 128 + c2) : 0u;
  float2 oA = *(float2*)(out + (size_t)n0 * 128 + c2);
  float2 oB = hasB ? *(float2*)(out + (size_t)(n0 + 1) * 128 + c2)
                   : make_float2(0.f, 0.f);

  auto process = [&](int off, int end, unsigned qv, float2& o) {
    if (end <= off) return;               // out keeps skip value
    const float q0 = bflo(qv), q1 = bfhi(qv);
    float s = 0.f, acc0 = 0.f, acc1 = 0.f;
    for (int c0 = off; c0 < end; c0 += 64) {
      const int cnt = min(64, end - c0);
      if (lane < cnt) lds_vo[wave][lane] = src_s[c0 + lane] * 128;
      const int lim = cnt - 1;
      for (int g0 = 0; g0 < cnt; g0 += 8) {
        unsigned evr[8], kvr[8], vvr[8];
#pragma unroll
        for (int g = 0; g < 8; ++g) {
          int jj = g0 + g;
          jj = (jj > lim) ? lim : jj;     // clamp: always a valid edge
          int vo = lds_vo[wave][jj];
          evr[g] = *(const unsigned*)(e_s + (size_t)(c0 + jj) * 128 + c2);
          kvr[g] = *(const unsigned*)(kb + vo + c2);
          vvr[g] = *(const unsigned*)(vb + vo + c2);
        }
#pragma unroll
        for (int g = 0; g < 8; ++g) {
          float part = q0 * (bflo(kvr[g]) + bflo(evr[g]))
                     + q1 * (bfhi(kvr[g]) + bfhi(evr[g]));
          part += __shfl_xor(part, 1);
          part += __shfl_xor(part, 2);
          part += __shfl_xor(part, 4);    // sum over the 8-lane head group
          float p = (g0 + g <= lim) ? __expf(part * 0.25f) : 0.f;
          s += p;
          acc0 = fmaf(p, bflo(vvr[g]) + bflo(evr[g]), acc0);
          acc1 = fmaf(p, bfhi(vvr[g]) + bfhi(evr[g]), acc1);
        }
      }
    }
    float r = 1.f / (s + 1e-16f);
    o.x += acc0 * r;
    o.y += acc1 * r;
  };

  process(offA, endA, qvA, oA);
  *(float2*)(out + (size_t)n0 * 128 + c2) = oA;
  if (hasB) {
    process(offB, endB, qvB, oB);
    *(float2*)(out + (size_t)(n0 + 1) * 128 + c2) = oB;
  }
}

extern "C" void kernel_launch(void* const* d_in, const int* in_sizes, int n_in,
                              void* d_out, int out_size, void* d_ws, size_t ws_size,
                              hipStream_t stream) {
  const float* feats = (const float*)d_in[0];
  const float* x     = (const float*)d_in[1];
  const float* lu    = (const float*)d_in[2];
  const int*   ei    = (const int*)d_in[3];
  const float* t     = (const float*)d_in[4];
  const float* msg   = (const float*)d_in[5];
  const float* tw    = (const float*)d_in[6];
  const float* tb    = (const float*)d_in[7];
  const float* Wq    = (const float*)d_in[8];
  const float* bq    = (const float*)d_in[9];
  const float* Wk    = (const float*)d_in[10];
  const float* bk    = (const float*)d_in[11];
  const float* Wv    = (const float*)d_in[12];
  const float* bv    = (const float*)d_in[13];
  const float* We    = (const float*)d_in[14];
  const float* Wskip = (const float*)d_in[15];
  const float* bskip = (const float*)d_in[16];
  float* out = (float*)d_out;
  const int N = in_sizes[2];
  const int E = in_sizes[4];

  char* ws = (char*)d_ws;
  short* wfrag = (short*)ws; ws += 5 * 2048 * 16;            // 160 KB
  short* qb    = (short*)ws; ws += (size_t)N * 128 * 2;
  short* kbuf  = (short*)ws; ws += (size_t)N * 128 * 2;
  short* vbuf  = (short*)ws; ws += (size_t)N * 128 * 2;
  short* e_s   = (short*)ws; ws += (size_t)E * 128 * 2;
  int* counts  = (int*)ws;   ws += (size_t)(N + 1) * 4;
  int* offs    = (int*)ws;   ws += (size_t)(N + 4) * 4;
  int* cursor  = (int*)ws;   ws += (size_t)N * 4;
  int* rank    = (int*)ws;   ws += (size_t)E * 4;
  int* src_s   = (int*)ws;   ws += (size_t)E * 4;
  int* bsum    = (int*)ws;   ws += 128 * 4;

  const int nb = (N + 1023) / 1024;
  const int nhist = (E + 255) / 256;

  hipMemsetAsync(counts, 0, (size_t)(N + 1) * 4, stream);

  PrepArgs pa;
  pa.W[0] = Wq; pa.W[1] = Wk; pa.W[2] = Wv; pa.W[3] = Wskip; pa.W[4] = We;
  k_front<<<40 + nhist, 256, 0, stream>>>(pa, wfrag, ei, counts, E);

  k_bsum<<<nb, 1024, 0, stream>>>(counts, bsum, N);
  k_scan2<<<nb, 1024, 0, stream>>>(counts, bsum, offs, cursor, N, nb);
  k_scatter<<<nhist, 256, 0, stream>>>(ei, cursor, rank, src_s, E);

  NodeArgs na;
  na.wf = wfrag;
  na.bias[0] = bq; na.bias[1] = bk; na.bias[2] = bv; na.bias[3] = bskip;
  na.outp[0] = qb; na.outp[1] = kbuf; na.outp[2] = vbuf; na.outp[3] = out;
  k_node<<<768, 256, 0, stream>>>(x, feats, na, N);

  k_egemm<<<512, 512, 0, stream>>>(lu, ei, t, msg, tw, tb, wfrag,
                                   rank, e_s, E);
  k_agg<<<(N + 7) / 8, 256, 0, stream>>>(offs, src_s, e_s, qb, kbuf, vbuf,
                                         out, N);
}

// Round 17
// 271.482 us; speedup vs baseline: 1.1075x; 1.0157x over previous
//
#include <hip/hip_runtime.h>
#include <math.h>

// ---------------------------------------------------------------------------
// TGN GraphAttentionEmbedding, MFMA bf16, dst-sorted dataflow (6 launches):
//   memset -> k_front(prep+hist) -> k_scan2(self-prefix) ->
//   k_nodescat(node GEMMs || scatter) -> k_egemm -> k_agg
// ---------------------------------------------------------------------------

typedef __attribute__((ext_vector_type(8))) short bf16x8;
typedef __attribute__((ext_vector_type(4))) float f32x4;

__device__ inline short f2bf(float f) {
  unsigned u = __float_as_uint(f);
  u += 0x7fff + ((u >> 16) & 1);     // round-to-nearest-even
  return (short)(u >> 16);
}
__device__ inline float bflo(unsigned u) { return __uint_as_float(u << 16); }
__device__ inline float bfhi(unsigned u) { return __uint_as_float(u & 0xffff0000u); }

// ---- front: W shuffle into MFMA B-frag layout (blocks 0-39) + dst hist ----
struct PrepArgs { const float* W[5]; };
__global__ void k_front(PrepArgs pa, short* __restrict__ wf,
                        const int* __restrict__ ei, int* __restrict__ counts,
                        int E) {
  const int b = blockIdx.x;
  if (b < 40) {
    int tid = b * 256 + threadIdx.x;
    if (tid >= 5 * 8 * 4 * 64) return;
    int lane = tid & 63;
    int kt = (tid >> 6) & 3;
    int nt = (tid >> 8) & 7;
    int mat = tid >> 11;
    const float* W = pa.W[mat];
    int n = nt * 16 + (lane & 15);
    short v[8];
#pragma unroll
    for (int j = 0; j < 8; ++j) {
      int k = kt * 32 + ((j >> 2) * 16) + ((lane >> 4) * 4) + (j & 3);
      v[j] = f2bf(W[k * 128 + n]);
    }
    ((uint4*)wf)[tid] = *(uint4*)v;
  } else {
    int i = (b - 40) * 256 + threadIdx.x;
    if (i < E) atomicAdd(&counts[ei[E + i]], 1);
  }
}

// scan with SELF-PREFIX: block b reduces counts[0..b*1024) itself (L2-hot),
// then does its local inclusive scan. Replaces k_bsum + k_bscan.
__global__ __launch_bounds__(1024) void k_scan2(const int* __restrict__ counts,
                                                int* __restrict__ offs,
                                                int* __restrict__ cursor,
                                                int N) {
  __shared__ int sh[1024];
  __shared__ int wsum[16];
  const int t = threadIdx.x;
  const int b = blockIdx.x;
  const int base_cnt = b << 10;
  int pv = 0;
  for (int i = t; i < base_cnt; i += 1024) pv += counts[i];
  for (int d = 32; d; d >>= 1) pv += __shfl_down(pv, d);
  if ((t & 63) == 0) wsum[t >> 6] = pv;
  __syncthreads();
  if (t == 0) {
    int s = 0;
    for (int j = 0; j < 16; ++j) s += wsum[j];
    wsum[0] = s;
  }
  __syncthreads();
  const int bpre = wsum[0];

  int i = base_cnt + t;
  int v = (i < N) ? counts[i] : 0;
  sh[t] = v;
  __syncthreads();
  for (int d = 1; d < 1024; d <<= 1) {
    int u = (t >= d) ? sh[t - d] : 0;
    __syncthreads();
    sh[t] += u;
    __syncthreads();
  }
  if (i < N) {
    int excl = bpre + sh[t] - v;
    offs[i] = excl;
    cursor[i] = excl;
    if (i == N - 1) offs[N] = excl + v;
  }
}

// ---- node GEMMs (blocks < nnode) || scatter (blocks >= nnode) -------------
// node: wave wv owns matrix wv, persistent 128-VGPR B-frag, grid-stride.
// scatter: rank[i] = sorted position of edge i; src_s[pos] = src. Runs in
// node's scheduling shadow (atomic-latency work, needs no occupancy).
struct NodeArgs {
  const short* wf;
  const float* bias[4];
  void* outp[4];
};

__global__ __launch_bounds__(256, 2) void k_nodescat(
    const float* __restrict__ x, const float* __restrict__ feats,
    NodeArgs na, int N, const int* __restrict__ ei, int* __restrict__ cursor,
    int* __restrict__ rank, int* __restrict__ src_s, int E, int nnode) {
  if (blockIdx.x >= nnode) {
    int i = (blockIdx.x - nnode) * 256 + threadIdx.x;
    if (i < E) {
      int pos = atomicAdd(&cursor[ei[E + i]], 1);
      rank[i] = pos;
      src_s[pos] = ei[i];
    }
    return;
  }
  __shared__ char lds[4][8192];           // per-wave transpose slice
  const int lane = threadIdx.x & 63;
  const int wv = threadIdx.x >> 6;        // matrix index: 0=q 1=k 2=v 3=skip
  char* myl = lds[wv];

  bf16x8 bfrag[8][4];
  const uint4* wfp = (const uint4*)na.wf + (size_t)wv * 2048;
#pragma unroll
  for (int nt = 0; nt < 8; ++nt)
#pragma unroll
    for (int kt = 0; kt < 4; ++kt)
      *(uint4*)&bfrag[nt][kt] = wfp[(nt * 4 + kt) * 64 + lane];

  float biasv[8];
#pragma unroll
  for (int nt = 0; nt < 8; ++nt) biasv[nt] = na.bias[wv][nt * 16 + (lane & 15)];
  void* op = na.outp[wv];

  const int arow = lane & 15;
  const int k4 = (lane >> 4) * 4;
  const int ntiles = (N + 15) / 16;
  for (int tile = blockIdx.x; tile < ntiles; tile += nnode) {
    int row = tile * 16 + arow;
    bool valid = row < N;
    const float* xr = x + (size_t)row * 64;
    const float* fr = feats + (size_t)row * 64;
    bf16x8 afrag[4];
#pragma unroll
    for (int kt = 0; kt < 4; ++kt) {
      const float* src = (kt < 2) ? xr : fr;
      int base = (kt & 1) * 32 + k4;
      float4 lo = valid ? *(const float4*)(src + base) : make_float4(0, 0, 0, 0);
      float4 hi = valid ? *(const float4*)(src + base + 16) : make_float4(0, 0, 0, 0);
      bf16x8 a;
      a[0] = f2bf(lo.x); a[1] = f2bf(lo.y); a[2] = f2bf(lo.z); a[3] = f2bf(lo.w);
      a[4] = f2bf(hi.x); a[5] = f2bf(hi.y); a[6] = f2bf(hi.z); a[7] = f2bf(hi.w);
      afrag[kt] = a;
    }
#pragma unroll
    for (int nt = 0; nt < 8; ++nt) {
      f32x4 acc = {0.f, 0.f, 0.f, 0.f};
#pragma unroll
      for (int kt = 0; kt < 4; ++kt)
        acc = __builtin_amdgcn_mfma_f32_16x16x32_bf16(afrag[kt], bfrag[nt][kt], acc, 0, 0, 0);
      int col = nt * 16 + (lane & 15);
#pragma unroll
      for (int reg = 0; reg < 4; ++reg) {
        int r = (lane >> 4) * 4 + reg;
        float vv = acc[reg] + biasv[nt];
        if (wv < 3) {
          int wb = (r * 256 + col * 2) ^ (((r >> 2) & 3) << 5);  // swizzled
          *(short*)(myl + wb) = f2bf(vv);
        } else {
          int wb = (r * 512 + col * 4) ^ (((r >> 2) & 3) << 6);  // swizzled
          *(float*)(myl + wb) = vv;
        }
      }
    }
    if (wv < 3) {
      short* opp = (short*)op;
#pragma unroll
      for (int i = 0; i < 8; ++i) {
        int r = i * 2 + (lane >> 5);
        int orow = tile * 16 + r;
        int rb = (r * 256 + (lane & 31) * 8) ^ (((r >> 2) & 3) << 5);
        uint2 val = *(const uint2*)(myl + rb);
        if (orow < N)
          *(uint2*)(opp + (size_t)orow * 128 + (lane & 31) * 4) = val;
      }
    } else {
      float* opp = (float*)op;
#pragma unroll
      for (int i = 0; i < 8; ++i) {
        int r = i * 2 + (lane >> 5);
        int orow = tile * 16 + r;
        int rb = (r * 512 + (lane & 31) * 16) ^ (((r >> 2) & 3) << 6);
        uint4 val = *(const uint4*)(myl + rb);
        if (orow < N)
          *(uint4*)(opp + (size_t)orow * 128 + (lane & 31) * 4) = val;
      }
    }
  }
}

// ---- edge GEMM, orig order, LDS-staged We-frag, index prefetch ------------
__global__ __launch_bounds__(512) void k_egemm(
    const float* __restrict__ lu, const int* __restrict__ ei,
    const float* __restrict__ t, const float* __restrict__ msg,
    const float* __restrict__ tw, const float* __restrict__ tb,
    const short* __restrict__ wf, const int* __restrict__ rank,
    short* __restrict__ e_s, int E) {
  __shared__ uint4 wlds[2048];            // 32 KB We fragment, block-shared
  __shared__ char tbuf[8][4096];          // per-wave 16x128 bf16 transpose
  const int lane = threadIdx.x & 63;
  const int wv = threadIdx.x >> 6;
  char* myl = tbuf[wv];

  for (int i = threadIdx.x; i < 2048; i += 512)
    wlds[i] = ((const uint4*)wf)[8192 + i];     // mat 4 = We
  __syncthreads();

  const int k4 = (lane >> 4) * 4;
  float twv[16], tbv[16];
#pragma unroll
  for (int kt = 0; kt < 2; ++kt) {
    int base = kt * 32 + k4;
    *(float4*)&twv[kt * 8]     = *(const float4*)(tw + base);
    *(float4*)&twv[kt * 8 + 4] = *(const float4*)(tw + base + 16);
    *(float4*)&tbv[kt * 8]     = *(const float4*)(tb + base);
    *(float4*)&tbv[kt * 8 + 4] = *(const float4*)(tb + base + 16);
  }

  const int ntiles = (E + 15) / 16;
  const int nwaves = gridDim.x * 8;
  int tile = blockIdx.x * 8 + wv;
  int p_src = 0, p_rank = 0;
  float p_t = 0.f;
  if (tile < ntiles && lane < 16 && tile * 16 + lane < E) {
    p_src  = ei[tile * 16 + lane];
    p_rank = rank[tile * 16 + lane];
    p_t    = t[tile * 16 + lane];
  }
  for (; tile < ntiles; tile += nwaves) {
    const int e0 = tile * 16;
    const int rank16 = p_rank;
    float relt = 0.f;
    if (lane < 16 && e0 + lane < E)
      relt = lu[p_src] - p_t;             // lu: 400KB L2-resident gather
    const int ntile = tile + nwaves;
    if (ntile < ntiles && lane < 16 && ntile * 16 + lane < E) {
      p_src  = ei[ntile * 16 + lane];
      p_rank = rank[ntile * 16 + lane];
      p_t    = t[ntile * 16 + lane];
    }
    const int r = lane & 15;
    float my_relt = __shfl(relt, r);
    bool rvalid = (e0 + r) < E;

    bf16x8 afrag[4];
#pragma unroll
    for (int kt = 0; kt < 2; ++kt) {
      bf16x8 a;
#pragma unroll
      for (int j = 0; j < 8; ++j)
        a[j] = f2bf(__cosf(my_relt * twv[kt * 8 + j] + tbv[kt * 8 + j]));
      afrag[kt] = a;
    }
    const float* mr = msg + (size_t)(e0 + r) * 64;   // streaming, coalesced
#pragma unroll
    for (int kt = 2; kt < 4; ++kt) {
      int base = (kt - 2) * 32 + k4;
      float4 lo = rvalid ? *(const float4*)(mr + base) : make_float4(0, 0, 0, 0);
      float4 hi = rvalid ? *(const float4*)(mr + base + 16) : make_float4(0, 0, 0, 0);
      bf16x8 a;
      a[0] = f2bf(lo.x); a[1] = f2bf(lo.y); a[2] = f2bf(lo.z); a[3] = f2bf(lo.w);
      a[4] = f2bf(hi.x); a[5] = f2bf(hi.y); a[6] = f2bf(hi.z); a[7] = f2bf(hi.w);
      afrag[kt] = a;
    }

#pragma unroll
    for (int nt = 0; nt < 8; ++nt) {
      bf16x8 bfrag[4];
#pragma unroll
      for (int kt = 0; kt < 4; ++kt)
        *(uint4*)&bfrag[kt] = wlds[(nt * 4 + kt) * 64 + lane];
      f32x4 acc = {0.f, 0.f, 0.f, 0.f};
#pragma unroll
      for (int kt = 0; kt < 4; ++kt)
        acc = __builtin_amdgcn_mfma_f32_16x16x32_bf16(afrag[kt], bfrag[kt], acc, 0, 0, 0);
      int col = nt * 16 + (lane & 15);
#pragma unroll
      for (int reg = 0; reg < 4; ++reg) {
        int rr = (lane >> 4) * 4 + reg;
        int wb = (rr * 256 + col * 2) ^ (((rr >> 2) & 3) << 5);  // swizzled
        *(short*)(myl + wb) = f2bf(acc[reg]);
      }
    }
#pragma unroll
    for (int i = 0; i < 8; ++i) {
      int rr = i * 2 + (lane >> 5);
      int er = e0 + rr;
      int drow = __shfl(rank16, rr);        // sorted row for this edge
      int rb = (rr * 256 + (lane & 31) * 8) ^ (((rr >> 2) & 3) << 5);
      uint2 val = *(const uint2*)(myl + rb);
      if (er < E)
        *(uint2*)(e_s + (size_t)drow * 128 + (lane & 31) * 4) = val;
    }
  }
}

// ---- per-dst aggregation: round-12 measured-best form ---------------------
__global__ __launch_bounds__(256) void k_agg(
    const int* __restrict__ offs, const int* __restrict__ src_s,
    const short* __restrict__ e_s, const short* __restrict__ qb,
    const short* __restrict__ kb, const short* __restrict__ vb,
    float* __restrict__ out, int N) {
  __shared__ int lds_vo[4][64];
  const int wave = threadIdx.x >> 6;
  const int lane = threadIdx.x & 63;
  const int n0 = (blockIdx.x * 4 + wave) * 2;
  if (n0 >= N) return;
  const int c2 = lane * 2;
  const bool hasB = (n0 + 1) < N;

  const int offA = offs[n0];
  const int endA = offs[n0 + 1];
  const int endB = hasB ? offs[n0 + 2] : endA;
  const int offB = endA;
  unsigned qvA = *(const unsigned*)(qb + (size_t)n0 * 128 + c2);
  unsigned qvB = hasB ? *(const unsigned*)(qb + (size_t)(n0 + 1) * 128 + c2) : 0u;
  float2 oA = *(float2*)(out + (size_t)n0 * 128 + c2);
  float2 oB = hasB ? *(float2*)(out + (size_t)(n0 + 1) * 128 + c2)
                   : make_float2(0.f, 0.f);

  auto process = [&](int off, int end, unsigned qv, float2& o) {
    if (end <= off) return;               // out keeps skip value
    const float q0 = bflo(qv), q1 = bfhi(qv);
    float s = 0.f, acc0 = 0.f, acc1 = 0.f;
    for (int c0 = off; c0 < end; c0 += 64) {
      const int cnt = min(64, end - c0);
      if (lane < cnt) lds_vo[wave][lane] = src_s[c0 + lane] * 128;
      const int lim = cnt - 1;
      for (int g0 = 0; g0 < cnt; g0 += 8) {
        unsigned evr[8], kvr[8], vvr[8];
#pragma unroll
        for (int g = 0; g < 8; ++g) {
          int jj = g0 + g;
          jj = (jj > lim) ? lim : jj;     // clamp: always a valid edge
          int vo = lds_vo[wave][jj];
          evr[g] = *(const unsigned*)(e_s + (size_t)(c0 + jj) * 128 + c2);
          kvr[g] = *(const unsigned*)(kb + vo + c2);
          vvr[g] = *(const unsigned*)(vb + vo + c2);
        }
#pragma unroll
        for (int g = 0; g < 8; ++g) {
          float part = q0 * (bflo(kvr[g]) + bflo(evr[g]))
                     + q1 * (bfhi(kvr[g]) + bfhi(evr[g]));
          part += __shfl_xor(part, 1);
          part += __shfl_xor(part, 2);
          part += __shfl_xor(part, 4);    // sum over the 8-lane head group
          float p = (g0 + g <= lim) ? __expf(part * 0.25f) : 0.f;
          s += p;
          acc0 = fmaf(p, bflo(vvr[g]) + bflo(evr[g]), acc0);
          acc1 = fmaf(p, bfhi(vvr[g]) + bfhi(evr[g]), acc1);
        }
      }
    }
    float r = 1.f / (s + 1e-16f);
    o.x += acc0 * r;
    o.y += acc1 * r;
  };

  process(offA, endA, qvA, oA);
  *(float2*)(out + (size_t)n0 * 128 + c2) = oA;
  if (hasB) {
    process(offB, endB, qvB, oB);
    *(float2*)(out + (size_t)(n0 + 1) * 128 + c2) = oB;
  }
}

extern "C" void kernel_launch(void* const* d_in, const int* in_sizes, int n_in,
                              void* d_out, int out_size, void* d_ws, size_t ws_size,
                              hipStream_t stream) {
  const float* feats = (const float*)d_in[0];
  const float* x     = (const float*)d_in[1];
  const float* lu    = (const float*)d_in[2];
  const int*   ei    = (const int*)d_in[3];
  const float* t     = (const float*)d_in[4];
  const float* msg   = (const float*)d_in[5];
  const float* tw    = (const float*)d_in[6];
  const float* tb    = (const float*)d_in[7];
  const float* Wq    = (const float*)d_in[8];
  const float* bq    = (const float*)d_in[9];
  const float* Wk    = (const float*)d_in[10];
  const float* bk    = (const float*)d_in[11];
  const float* Wv    = (const float*)d_in[12];
  const float* bv    = (const float*)d_in[13];
  const float* We    = (const float*)d_in[14];
  const float* Wskip = (const float*)d_in[15];
  const float* bskip = (const float*)d_in[16];
  float* out = (float*)d_out;
  const int N = in_sizes[2];
  const int E = in_sizes[4];

  char* ws = (char*)d_ws;
  short* wfrag = (short*)ws; ws += 5 * 2048 * 16;            // 160 KB
  short* qb    = (short*)ws; ws += (size_t)N * 128 * 2;
  short* kbuf  = (short*)ws; ws += (size_t)N * 128 * 2;
  short* vbuf  = (short*)ws; ws += (size_t)N * 128 * 2;
  short* e_s   = (short*)ws; ws += (size_t)E * 128 * 2;
  int* counts  = (int*)ws;   ws += (size_t)(N + 1) * 4;
  int* offs    = (int*)ws;   ws += (size_t)(N + 4) * 4;
  int* cursor  = (int*)ws;   ws += (size_t)N * 4;
  int* rank    = (int*)ws;   ws += (size_t)E * 4;
  int* src_s   = (int*)ws;   ws += (size_t)E * 4;

  const int nb = (N + 1023) / 1024;
  const int nhist = (E + 255) / 256;
  const int nnode = 768;

  hipMemsetAsync(counts, 0, (size_t)(N + 1) * 4, stream);

  PrepArgs pa;
  pa.W[0] = Wq; pa.W[1] = Wk; pa.W[2] = Wv; pa.W[3] = Wskip; pa.W[4] = We;
  k_front<<<40 + nhist, 256, 0, stream>>>(pa, wfrag, ei, counts, E);

  k_scan2<<<nb, 1024, 0, stream>>>(counts, offs, cursor, N);

  NodeArgs na;
  na.wf = wfrag;
  na.bias[0] = bq; na.bias[1] = bk; na.bias[2] = bv; na.bias[3] = bskip;
  na.outp[0] = qb; na.outp[1] = kbuf; na.outp[2] = vbuf; na.outp[3] = out;
  k_nodescat<<<nnode + nhist, 256, 0, stream>>>(x, feats, na, N, ei, cursor,
                                                rank, src_s, E, nnode);

  k_egemm<<<512, 512, 0, stream>>>(lu, ei, t, msg, tw, tb, wfrag,
                                   rank, e_s, E);
  k_agg<<<(N + 7) / 8, 256, 0, stream>>>(offs, src_s, e_s, qb, kbuf, vbuf,
                                         out, N);
}

// Round 18
// 268.723 us; speedup vs baseline: 1.1188x; 1.0103x over previous
//
#include <hip/hip_runtime.h>
#include <math.h>

// ---------------------------------------------------------------------------
// TGN GraphAttentionEmbedding, MFMA bf16, dst-sorted dataflow (6 launches):
//   memset -> k_front(prep+hist) -> k_scan2(self-prefix) ->
//   k_nodescat(node GEMMs || scatter) -> k_egemm -> k_agg
// ---------------------------------------------------------------------------

typedef __attribute__((ext_vector_type(8))) short bf16x8;
typedef __attribute__((ext_vector_type(4))) float f32x4;

__device__ inline short f2bf(float f) {
  unsigned u = __float_as_uint(f);
  u += 0x7fff + ((u >> 16) & 1);     // round-to-nearest-even
  return (short)(u >> 16);
}
__device__ inline float bflo(unsigned u) { return __uint_as_float(u << 16); }
__device__ inline float bfhi(unsigned u) { return __uint_as_float(u & 0xffff0000u); }

// ---- front: W shuffle into MFMA B-frag layout (blocks 0-39) + dst hist ----
struct PrepArgs { const float* W[5]; };
__global__ void k_front(PrepArgs pa, short* __restrict__ wf,
                        const int* __restrict__ ei, int* __restrict__ counts,
                        int E) {
  const int b = blockIdx.x;
  if (b < 40) {
    int tid = b * 256 + threadIdx.x;
    if (tid >= 5 * 8 * 4 * 64) return;
    int lane = tid & 63;
    int kt = (tid >> 6) & 3;
    int nt = (tid >> 8) & 7;
    int mat = tid >> 11;
    const float* W = pa.W[mat];
    int n = nt * 16 + (lane & 15);
    short v[8];
#pragma unroll
    for (int j = 0; j < 8; ++j) {
      int k = kt * 32 + ((j >> 2) * 16) + ((lane >> 4) * 4) + (j & 3);
      v[j] = f2bf(W[k * 128 + n]);
    }
    ((uint4*)wf)[tid] = *(uint4*)v;
  } else {
    int i = (b - 40) * 256 + threadIdx.x;
    if (i < E) atomicAdd(&counts[ei[E + i]], 1);
  }
}

// scan with SELF-PREFIX: block b reduces counts[0..b*1024) itself (L2-hot),
// then does its local inclusive scan.
__global__ __launch_bounds__(1024) void k_scan2(const int* __restrict__ counts,
                                                int* __restrict__ offs,
                                                int* __restrict__ cursor,
                                                int N) {
  __shared__ int sh[1024];
  __shared__ int wsum[16];
  const int t = threadIdx.x;
  const int b = blockIdx.x;
  const int base_cnt = b << 10;
  int pv = 0;
  for (int i = t; i < base_cnt; i += 1024) pv += counts[i];
  for (int d = 32; d; d >>= 1) pv += __shfl_down(pv, d);
  if ((t & 63) == 0) wsum[t >> 6] = pv;
  __syncthreads();
  if (t == 0) {
    int s = 0;
    for (int j = 0; j < 16; ++j) s += wsum[j];
    wsum[0] = s;
  }
  __syncthreads();
  const int bpre = wsum[0];

  int i = base_cnt + t;
  int v = (i < N) ? counts[i] : 0;
  sh[t] = v;
  __syncthreads();
  for (int d = 1; d < 1024; d <<= 1) {
    int u = (t >= d) ? sh[t - d] : 0;
    __syncthreads();
    sh[t] += u;
    __syncthreads();
  }
  if (i < N) {
    int excl = bpre + sh[t] - v;
    offs[i] = excl;
    cursor[i] = excl;
    if (i == N - 1) offs[N] = excl + v;
  }
}

// ---- node GEMMs (blocks < nnode) || scatter (blocks >= nnode) -------------
struct NodeArgs {
  const short* wf;
  const float* bias[4];
  void* outp[4];
};

__global__ __launch_bounds__(256, 2) void k_nodescat(
    const float* __restrict__ x, const float* __restrict__ feats,
    NodeArgs na, int N, const int* __restrict__ ei, int* __restrict__ cursor,
    int* __restrict__ rank, int* __restrict__ src_s, int E, int nnode) {
  if (blockIdx.x >= nnode) {
    int i = (blockIdx.x - nnode) * 256 + threadIdx.x;
    if (i < E) {
      int pos = atomicAdd(&cursor[ei[E + i]], 1);
      rank[i] = pos;
      src_s[pos] = ei[i];
    }
    return;
  }
  __shared__ char lds[4][8192];           // per-wave transpose slice
  const int lane = threadIdx.x & 63;
  const int wv = threadIdx.x >> 6;        // matrix index: 0=q 1=k 2=v 3=skip
  char* myl = lds[wv];

  bf16x8 bfrag[8][4];
  const uint4* wfp = (const uint4*)na.wf + (size_t)wv * 2048;
#pragma unroll
  for (int nt = 0; nt < 8; ++nt)
#pragma unroll
    for (int kt = 0; kt < 4; ++kt)
      *(uint4*)&bfrag[nt][kt] = wfp[(nt * 4 + kt) * 64 + lane];

  float biasv[8];
#pragma unroll
  for (int nt = 0; nt < 8; ++nt) biasv[nt] = na.bias[wv][nt * 16 + (lane & 15)];
  void* op = na.outp[wv];

  const int arow = lane & 15;
  const int k4 = (lane >> 4) * 4;
  const int ntiles = (N + 15) / 16;
  for (int tile = blockIdx.x; tile < ntiles; tile += nnode) {
    int row = tile * 16 + arow;
    bool valid = row < N;
    const float* xr = x + (size_t)row * 64;
    const float* fr = feats + (size_t)row * 64;
    bf16x8 afrag[4];
#pragma unroll
    for (int kt = 0; kt < 4; ++kt) {
      const float* src = (kt < 2) ? xr : fr;
      int base = (kt & 1) * 32 + k4;
      float4 lo = valid ? *(const float4*)(src + base) : make_float4(0, 0, 0, 0);
      float4 hi = valid ? *(const float4*)(src + base + 16) : make_float4(0, 0, 0, 0);
      bf16x8 a;
      a[0] = f2bf(lo.x); a[1] = f2bf(lo.y); a[2] = f2bf(lo.z); a[3] = f2bf(lo.w);
      a[4] = f2bf(hi.x); a[5] = f2bf(hi.y); a[6] = f2bf(hi.z); a[7] = f2bf(hi.w);
      afrag[kt] = a;
    }
#pragma unroll
    for (int nt = 0; nt < 8; ++nt) {
      f32x4 acc = {0.f, 0.f, 0.f, 0.f};
#pragma unroll
      for (int kt = 0; kt < 4; ++kt)
        acc = __builtin_amdgcn_mfma_f32_16x16x32_bf16(afrag[kt], bfrag[nt][kt], acc, 0, 0, 0);
      int col = nt * 16 + (lane & 15);
#pragma unroll
      for (int reg = 0; reg < 4; ++reg) {
        int r = (lane >> 4) * 4 + reg;
        float vv = acc[reg] + biasv[nt];
        if (wv < 3) {
          int wb = (r * 256 + col * 2) ^ (((r >> 2) & 3) << 5);  // swizzled
          *(short*)(myl + wb) = f2bf(vv);
        } else {
          int wb = (r * 512 + col * 4) ^ (((r >> 2) & 3) << 6);  // swizzled
          *(float*)(myl + wb) = vv;
        }
      }
    }
    if (wv < 3) {
      short* opp = (short*)op;
#pragma unroll
      for (int i = 0; i < 8; ++i) {
        int r = i * 2 + (lane >> 5);
        int orow = tile * 16 + r;
        int rb = (r * 256 + (lane & 31) * 8) ^ (((r >> 2) & 3) << 5);
        uint2 val = *(const uint2*)(myl + rb);
        if (orow < N)
          *(uint2*)(opp + (size_t)orow * 128 + (lane & 31) * 4) = val;
      }
    } else {
      float* opp = (float*)op;
#pragma unroll
      for (int i = 0; i < 8; ++i) {
        int r = i * 2 + (lane >> 5);
        int orow = tile * 16 + r;
        int rb = (r * 512 + (lane & 31) * 16) ^ (((r >> 2) & 3) << 6);
        uint4 val = *(const uint4*)(myl + rb);
        if (orow < N)
          *(uint4*)(opp + (size_t)orow * 128 + (lane & 31) * 4) = val;
      }
    }
  }
}

// ---- edge GEMM, orig order, LDS-staged We-frag, index prefetch ------------
__global__ __launch_bounds__(512) void k_egemm(
    const float* __restrict__ lu, const int* __restrict__ ei,
    const float* __restrict__ t, const float* __restrict__ msg,
    const float* __restrict__ tw, const float* __restrict__ tb,
    const short* __restrict__ wf, const int* __restrict__ rank,
    short* __restrict__ e_s, int E) {
  __shared__ uint4 wlds[2048];            // 32 KB We fragment, block-shared
  __shared__ char tbuf[8][4096];          // per-wave 16x128 bf16 transpose
  const int lane = threadIdx.x & 63;
  const int wv = threadIdx.x >> 6;
  char* myl = tbuf[wv];

  for (int i = threadIdx.x; i < 2048; i += 512)
    wlds[i] = ((const uint4*)wf)[8192 + i];     // mat 4 = We
  __syncthreads();

  const int k4 = (lane >> 4) * 4;
  float twv[16], tbv[16];
#pragma unroll
  for (int kt = 0; kt < 2; ++kt) {
    int base = kt * 32 + k4;
    *(float4*)&twv[kt * 8]     = *(const float4*)(tw + base);
    *(float4*)&twv[kt * 8 + 4] = *(const float4*)(tw + base + 16);
    *(float4*)&tbv[kt * 8]     = *(const float4*)(tb + base);
    *(float4*)&tbv[kt * 8 + 4] = *(const float4*)(tb + base + 16);
  }

  const int ntiles = (E + 15) / 16;
  const int nwaves = gridDim.x * 8;
  int tile = blockIdx.x * 8 + wv;
  int p_src = 0, p_rank = 0;
  float p_t = 0.f;
  if (tile < ntiles && lane < 16 && tile * 16 + lane < E) {
    p_src  = ei[tile * 16 + lane];
    p_rank = rank[tile * 16 + lane];
    p_t    = t[tile * 16 + lane];
  }
  for (; tile < ntiles; tile += nwaves) {
    const int e0 = tile * 16;
    const int rank16 = p_rank;
    float relt = 0.f;
    if (lane < 16 && e0 + lane < E)
      relt = lu[p_src] - p_t;             // lu: 400KB L2-resident gather
    const int ntile = tile + nwaves;
    if (ntile < ntiles && lane < 16 && ntile * 16 + lane < E) {
      p_src  = ei[ntile * 16 + lane];
      p_rank = rank[ntile * 16 + lane];
      p_t    = t[ntile * 16 + lane];
    }
    const int r = lane & 15;
    float my_relt = __shfl(relt, r);
    bool rvalid = (e0 + r) < E;

    bf16x8 afrag[4];
#pragma unroll
    for (int kt = 0; kt < 2; ++kt) {
      bf16x8 a;
#pragma unroll
      for (int j = 0; j < 8; ++j)
        a[j] = f2bf(__cosf(my_relt * twv[kt * 8 + j] + tbv[kt * 8 + j]));
      afrag[kt] = a;
    }
    const float* mr = msg + (size_t)(e0 + r) * 64;   // streaming, coalesced
#pragma unroll
    for (int kt = 2; kt < 4; ++kt) {
      int base = (kt - 2) * 32 + k4;
      float4 lo = rvalid ? *(const float4*)(mr + base) : make_float4(0, 0, 0, 0);
      float4 hi = rvalid ? *(const float4*)(mr + base + 16) : make_float4(0, 0, 0, 0);
      bf16x8 a;
      a[0] = f2bf(lo.x); a[1] = f2bf(lo.y); a[2] = f2bf(lo.z); a[3] = f2bf(lo.w);
      a[4] = f2bf(hi.x); a[5] = f2bf(hi.y); a[6] = f2bf(hi.z); a[7] = f2bf(hi.w);
      afrag[kt] = a;
    }

#pragma unroll
    for (int nt = 0; nt < 8; ++nt) {
      bf16x8 bfrag[4];
#pragma unroll
      for (int kt = 0; kt < 4; ++kt)
        *(uint4*)&bfrag[kt] = wlds[(nt * 4 + kt) * 64 + lane];
      f32x4 acc = {0.f, 0.f, 0.f, 0.f};
#pragma unroll
      for (int kt = 0; kt < 4; ++kt)
        acc = __builtin_amdgcn_mfma_f32_16x16x32_bf16(afrag[kt], bfrag[kt], acc, 0, 0, 0);
      int col = nt * 16 + (lane & 15);
#pragma unroll
      for (int reg = 0; reg < 4; ++reg) {
        int rr = (lane >> 4) * 4 + reg;
        int wb = (rr * 256 + col * 2) ^ (((rr >> 2) & 3) << 5);  // swizzled
        *(short*)(myl + wb) = f2bf(acc[reg]);
      }
    }
#pragma unroll
    for (int i = 0; i < 8; ++i) {
      int rr = i * 2 + (lane >> 5);
      int er = e0 + rr;
      int drow = __shfl(rank16, rr);        // sorted row for this edge
      int rb = (rr * 256 + (lane & 31) * 8) ^ (((rr >> 2) & 3) << 5);
      uint2 val = *(const uint2*)(myl + rb);
      if (er < E)
        *(uint2*)(e_s + (size_t)drow * 128 + (lane & 31) * 4) = val;
    }
  }
}

// ---- per-dst aggregation: r12 form + affine e_s (padded) + 0.25-fold ------
// lane owns channel pair c2=2*lane -> head h=lane>>3. e_s padded by 64 rows:
// e_s loads use raw j (affine, immediate offsets); vo keeps clamped LDS
// broadcast. Fake-slot garbage is finite bf16, masked via p=0.
__global__ __launch_bounds__(256) void k_agg(
    const int* __restrict__ offs, const int* __restrict__ src_s,
    const short* __restrict__ e_s, const short* __restrict__ qb,
    const short* __restrict__ kb, const short* __restrict__ vb,
    float* __restrict__ out, int N) {
  __shared__ int lds_vo[4][64];
  const int wave = threadIdx.x >> 6;
  const int lane = threadIdx.x & 63;
  const int n0 = (blockIdx.x * 4 + wave) * 2;
  if (n0 >= N) return;
  const int c2 = lane * 2;
  const bool hasB = (n0 + 1) < N;

  const int offA = offs[n0];
  const int endA = offs[n0 + 1];
  const int endB = hasB ? offs[n0 + 2] : endA;
  const int offB = endA;
  unsigned qvA = *(const unsigned*)(qb + (size_t)n0 * 128 + c2);
  unsigned qvB = hasB ? *(const unsigned*)(qb + (size_t)(n0 + 1) * 128 + c2) : 0u;
  float2 oA = *(float2*)(out + (size_t)n0 * 128 + c2);
  float2 oB = hasB ? *(float2*)(out + (size_t)(n0 + 1) * 128 + c2)
                   : make_float2(0.f, 0.f);

  auto process = [&](int off, int end, unsigned qv, float2& o) {
    if (end <= off) return;               // out keeps skip value
    const float q0 = bflo(qv) * 0.25f;    // fold /sqrt(HEAD_DIM) into q
    const float q1 = bfhi(qv) * 0.25f;
    float s = 0.f, acc0 = 0.f, acc1 = 0.f;
    for (int c0 = off; c0 < end; c0 += 64) {
      const int cnt = min(64, end - c0);
      if (lane < cnt) lds_vo[wave][lane] = src_s[c0 + lane] * 128;
      const int lim = cnt - 1;
      for (int g0 = 0; g0 < cnt; g0 += 8) {
        const short* ebase = e_s + (size_t)(c0 + g0) * 128 + c2;
        unsigned evr[8], kvr[8], vvr[8];
#pragma unroll
        for (int g = 0; g < 8; ++g) {
          int jj = g0 + g;
          jj = (jj > lim) ? lim : jj;     // clamp for k/v only
          int vo = lds_vo[wave][jj];
          evr[g] = *(const unsigned*)(ebase + g * 128);   // affine (padded)
          kvr[g] = *(const unsigned*)(kb + vo + c2);
          vvr[g] = *(const unsigned*)(vb + vo + c2);
        }
#pragma unroll
        for (int g = 0; g < 8; ++g) {
          float part = q0 * (bflo(kvr[g]) + bflo(evr[g]))
                     + q1 * (bfhi(kvr[g]) + bfhi(evr[g]));
          part += __shfl_xor(part, 1);
          part += __shfl_xor(part, 2);
          part += __shfl_xor(part, 4);    // sum over the 8-lane head group
          float p = (g0 + g <= lim) ? __expf(part) : 0.f;
          s += p;
          acc0 = fmaf(p, bflo(vvr[g]) + bflo(evr[g]), acc0);
          acc1 = fmaf(p, bfhi(vvr[g]) + bfhi(evr[g]), acc1);
        }
      }
    }
    float r = 1.f / (s + 1e-16f);
    o.x += acc0 * r;
    o.y += acc1 * r;
  };

  process(offA, endA, qvA, oA);
  *(float2*)(out + (size_t)n0 * 128 + c2) = oA;
  if (hasB) {
    process(offB, endB, qvB, oB);
    *(float2*)(out + (size_t)(n0 + 1) * 128 + c2) = oB;
  }
}

extern "C" void kernel_launch(void* const* d_in, const int* in_sizes, int n_in,
                              void* d_out, int out_size, void* d_ws, size_t ws_size,
                              hipStream_t stream) {
  const float* feats = (const float*)d_in[0];
  const float* x     = (const float*)d_in[1];
  const float* lu    = (const float*)d_in[2];
  const int*   ei    = (const int*)d_in[3];
  const float* t     = (const float*)d_in[4];
  const float* msg   = (const float*)d_in[5];
  const float* tw    = (const float*)d_in[6];
  const float* tb    = (const float*)d_in[7];
  const float* Wq    = (const float*)d_in[8];
  const float* bq    = (const float*)d_in[9];
  const float* Wk    = (const float*)d_in[10];
  const float* bk    = (const float*)d_in[11];
  const float* Wv    = (const float*)d_in[12];
  const float* bv    = (const float*)d_in[13];
  const float* We    = (const float*)d_in[14];
  const float* Wskip = (const float*)d_in[15];
  const float* bskip = (const float*)d_in[16];
  float* out = (float*)d_out;
  const int N = in_sizes[2];
  const int E = in_sizes[4];

  char* ws = (char*)d_ws;
  short* wfrag = (short*)ws; ws += 5 * 2048 * 16;            // 160 KB
  short* qb    = (short*)ws; ws += (size_t)N * 128 * 2;
  short* kbuf  = (short*)ws; ws += (size_t)N * 128 * 2;
  short* vbuf  = (short*)ws; ws += (size_t)N * 128 * 2;
  short* e_s   = (short*)ws; ws += (size_t)(E + 64) * 128 * 2;  // +64 pad rows
  int* counts  = (int*)ws;   ws += (size_t)(N + 1) * 4;
  int* offs    = (int*)ws;   ws += (size_t)(N + 4) * 4;
  int* cursor  = (int*)ws;   ws += (size_t)N * 4;
  int* rank    = (int*)ws;   ws += (size_t)E * 4;
  int* src_s   = (int*)ws;   ws += (size_t)E * 4;

  const int nb = (N + 1023) / 1024;
  const int nhist = (E + 255) / 256;
  const int nnode = 512;

  hipMemsetAsync(counts, 0, (size_t)(N + 1) * 4, stream);

  PrepArgs pa;
  pa.W[0] = Wq; pa.W[1] = Wk; pa.W[2] = Wv; pa.W[3] = Wskip; pa.W[4] = We;
  k_front<<<40 + nhist, 256, 0, stream>>>(pa, wfrag, ei, counts, E);

  k_scan2<<<nb, 1024, 0, stream>>>(counts, offs, cursor, N);

  NodeArgs na;
  na.wf = wfrag;
  na.bias[0] = bq; na.bias[1] = bk; na.bias[2] = bv; na.bias[3] = bskip;
  na.outp[0] = qb; na.outp[1] = kbuf; na.outp[2] = vbuf; na.outp[3] = out;
  k_nodescat<<<nnode + nhist, 256, 0, stream>>>(x, feats, na, N, ei, cursor,
                                                rank, src_s, E, nnode);

  k_egemm<<<512, 512, 0, stream>>>(lu, ei, t, msg, tw, tb, wfrag,
                                   rank, e_s, E);
  k_agg<<<(N + 7) / 8, 256, 0, stream>>>(offs, src_s, e_s, qb, kbuf, vbuf,
                                         out, N);
}

// Round 19
// 247.681 us; speedup vs baseline: 1.2139x; 1.0850x over previous
//
#include <hip/hip_runtime.h>
#include <math.h>

// ---------------------------------------------------------------------------
// TGN GraphAttentionEmbedding, MFMA bf16, dst-sorted dataflow (6 launches):
//   memset -> k_front(prep+hist) -> k_scan2(self-prefix) ->
//   k_nodescat(node GEMMs || scatter) -> k_egemm -> k_agg
// Skip path: node writes bf16 skipb; agg does pure store out = skip + attn.
// ---------------------------------------------------------------------------

typedef __attribute__((ext_vector_type(8))) short bf16x8;
typedef __attribute__((ext_vector_type(4))) float f32x4;

__device__ inline short f2bf(float f) {
  unsigned u = __float_as_uint(f);
  u += 0x7fff + ((u >> 16) & 1);     // round-to-nearest-even
  return (short)(u >> 16);
}
__device__ inline float bflo(unsigned u) { return __uint_as_float(u << 16); }
__device__ inline float bfhi(unsigned u) { return __uint_as_float(u & 0xffff0000u); }

// ---- front: W shuffle into MFMA B-frag layout (blocks 0-39) + dst hist ----
struct PrepArgs { const float* W[5]; };
__global__ void k_front(PrepArgs pa, short* __restrict__ wf,
                        const int* __restrict__ ei, int* __restrict__ counts,
                        int E) {
  const int b = blockIdx.x;
  if (b < 40) {
    int tid = b * 256 + threadIdx.x;
    if (tid >= 5 * 8 * 4 * 64) return;
    int lane = tid & 63;
    int kt = (tid >> 6) & 3;
    int nt = (tid >> 8) & 7;
    int mat = tid >> 11;
    const float* W = pa.W[mat];
    int n = nt * 16 + (lane & 15);
    short v[8];
#pragma unroll
    for (int j = 0; j < 8; ++j) {
      int k = kt * 32 + ((j >> 2) * 16) + ((lane >> 4) * 4) + (j & 3);
      v[j] = f2bf(W[k * 128 + n]);
    }
    ((uint4*)wf)[tid] = *(uint4*)v;
  } else {
    int i = (b - 40) * 256 + threadIdx.x;
    if (i < E) atomicAdd(&counts[ei[E + i]], 1);
  }
}

// scan with SELF-PREFIX: block b reduces counts[0..b*1024) itself (L2-hot),
// then does its local inclusive scan.
__global__ __launch_bounds__(1024) void k_scan2(const int* __restrict__ counts,
                                                int* __restrict__ offs,
                                                int* __restrict__ cursor,
                                                int N) {
  __shared__ int sh[1024];
  __shared__ int wsum[16];
  const int t = threadIdx.x;
  const int b = blockIdx.x;
  const int base_cnt = b << 10;
  int pv = 0;
  for (int i = t; i < base_cnt; i += 1024) pv += counts[i];
  for (int d = 32; d; d >>= 1) pv += __shfl_down(pv, d);
  if ((t & 63) == 0) wsum[t >> 6] = pv;
  __syncthreads();
  if (t == 0) {
    int s = 0;
    for (int j = 0; j < 16; ++j) s += wsum[j];
    wsum[0] = s;
  }
  __syncthreads();
  const int bpre = wsum[0];

  int i = base_cnt + t;
  int v = (i < N) ? counts[i] : 0;
  sh[t] = v;
  __syncthreads();
  for (int d = 1; d < 1024; d <<= 1) {
    int u = (t >= d) ? sh[t - d] : 0;
    __syncthreads();
    sh[t] += u;
    __syncthreads();
  }
  if (i < N) {
    int excl = bpre + sh[t] - v;
    offs[i] = excl;
    cursor[i] = excl;
    if (i == N - 1) offs[N] = excl + v;
  }
}

// ---- node GEMMs (blocks < nnode) || scatter (blocks >= nnode) -------------
// All 4 outputs (q,k,v,skip) now bf16 -> uniform transpose/store path.
struct NodeArgs {
  const short* wf;
  const float* bias[4];
  short* outp[4];
};

__global__ __launch_bounds__(256, 2) void k_nodescat(
    const float* __restrict__ x, const float* __restrict__ feats,
    NodeArgs na, int N, const int* __restrict__ ei, int* __restrict__ cursor,
    int* __restrict__ rank, int* __restrict__ src_s, int E, int nnode) {
  if (blockIdx.x >= nnode) {
    int i = (blockIdx.x - nnode) * 256 + threadIdx.x;
    if (i < E) {
      int pos = atomicAdd(&cursor[ei[E + i]], 1);
      rank[i] = pos;
      src_s[pos] = ei[i];
    }
    return;
  }
  __shared__ char lds[4][4096];           // per-wave bf16 transpose slice
  const int lane = threadIdx.x & 63;
  const int wv = threadIdx.x >> 6;        // matrix index: 0=q 1=k 2=v 3=skip
  char* myl = lds[wv];

  bf16x8 bfrag[8][4];
  const uint4* wfp = (const uint4*)na.wf + (size_t)wv * 2048;
#pragma unroll
  for (int nt = 0; nt < 8; ++nt)
#pragma unroll
    for (int kt = 0; kt < 4; ++kt)
      *(uint4*)&bfrag[nt][kt] = wfp[(nt * 4 + kt) * 64 + lane];

  float biasv[8];
#pragma unroll
  for (int nt = 0; nt < 8; ++nt) biasv[nt] = na.bias[wv][nt * 16 + (lane & 15)];
  short* op = na.outp[wv];

  const int arow = lane & 15;
  const int k4 = (lane >> 4) * 4;
  const int ntiles = (N + 15) / 16;
  for (int tile = blockIdx.x; tile < ntiles; tile += nnode) {
    int row = tile * 16 + arow;
    bool valid = row < N;
    const float* xr = x + (size_t)row * 64;
    const float* fr = feats + (size_t)row * 64;
    bf16x8 afrag[4];
#pragma unroll
    for (int kt = 0; kt < 4; ++kt) {
      const float* src = (kt < 2) ? xr : fr;
      int base = (kt & 1) * 32 + k4;
      float4 lo = valid ? *(const float4*)(src + base) : make_float4(0, 0, 0, 0);
      float4 hi = valid ? *(const float4*)(src + base + 16) : make_float4(0, 0, 0, 0);
      bf16x8 a;
      a[0] = f2bf(lo.x); a[1] = f2bf(lo.y); a[2] = f2bf(lo.z); a[3] = f2bf(lo.w);
      a[4] = f2bf(hi.x); a[5] = f2bf(hi.y); a[6] = f2bf(hi.z); a[7] = f2bf(hi.w);
      afrag[kt] = a;
    }
#pragma unroll
    for (int nt = 0; nt < 8; ++nt) {
      f32x4 acc = {0.f, 0.f, 0.f, 0.f};
#pragma unroll
      for (int kt = 0; kt < 4; ++kt)
        acc = __builtin_amdgcn_mfma_f32_16x16x32_bf16(afrag[kt], bfrag[nt][kt], acc, 0, 0, 0);
      int col = nt * 16 + (lane & 15);
#pragma unroll
      for (int reg = 0; reg < 4; ++reg) {
        int r = (lane >> 4) * 4 + reg;
        int wb = (r * 256 + col * 2) ^ (((r >> 2) & 3) << 5);    // swizzled
        *(short*)(myl + wb) = f2bf(acc[reg] + biasv[nt]);
      }
    }
#pragma unroll
    for (int i = 0; i < 8; ++i) {
      int r = i * 2 + (lane >> 5);
      int orow = tile * 16 + r;
      int rb = (r * 256 + (lane & 31) * 8) ^ (((r >> 2) & 3) << 5);
      uint2 val = *(const uint2*)(myl + rb);
      if (orow < N)
        *(uint2*)(op + (size_t)orow * 128 + (lane & 31) * 4) = val;
    }
  }
}

// ---- edge GEMM, orig order, LDS-staged We-frag, index prefetch ------------
__global__ __launch_bounds__(512) void k_egemm(
    const float* __restrict__ lu, const int* __restrict__ ei,
    const float* __restrict__ t, const float* __restrict__ msg,
    const float* __restrict__ tw, const float* __restrict__ tb,
    const short* __restrict__ wf, const int* __restrict__ rank,
    short* __restrict__ e_s, int E) {
  __shared__ uint4 wlds[2048];            // 32 KB We fragment, block-shared
  __shared__ char tbuf[8][4096];          // per-wave 16x128 bf16 transpose
  const int lane = threadIdx.x & 63;
  const int wv = threadIdx.x >> 6;
  char* myl = tbuf[wv];

  for (int i = threadIdx.x; i < 2048; i += 512)
    wlds[i] = ((const uint4*)wf)[8192 + i];     // mat 4 = We
  __syncthreads();

  const int k4 = (lane >> 4) * 4;
  float twv[16], tbv[16];
#pragma unroll
  for (int kt = 0; kt < 2; ++kt) {
    int base = kt * 32 + k4;
    *(float4*)&twv[kt * 8]     = *(const float4*)(tw + base);
    *(float4*)&twv[kt * 8 + 4] = *(const float4*)(tw + base + 16);
    *(float4*)&tbv[kt * 8]     = *(const float4*)(tb + base);
    *(float4*)&tbv[kt * 8 + 4] = *(const float4*)(tb + base + 16);
  }

  const int ntiles = (E + 15) / 16;
  const int nwaves = gridDim.x * 8;
  int tile = blockIdx.x * 8 + wv;
  int p_src = 0, p_rank = 0;
  float p_t = 0.f;
  if (tile < ntiles && lane < 16 && tile * 16 + lane < E) {
    p_src  = ei[tile * 16 + lane];
    p_rank = rank[tile * 16 + lane];
    p_t    = t[tile * 16 + lane];
  }
  for (; tile < ntiles; tile += nwaves) {
    const int e0 = tile * 16;
    const int rank16 = p_rank;
    float relt = 0.f;
    if (lane < 16 && e0 + lane < E)
      relt = lu[p_src] - p_t;             // lu: 400KB L2-resident gather
    const int ntile = tile + nwaves;
    if (ntile < ntiles && lane < 16 && ntile * 16 + lane < E) {
      p_src  = ei[ntile * 16 + lane];
      p_rank = rank[ntile * 16 + lane];
      p_t    = t[ntile * 16 + lane];
    }
    const int r = lane & 15;
    float my_relt = __shfl(relt, r);
    bool rvalid = (e0 + r) < E;

    bf16x8 afrag[4];
#pragma unroll
    for (int kt = 0; kt < 2; ++kt) {
      bf16x8 a;
#pragma unroll
      for (int j = 0; j < 8; ++j)
        a[j] = f2bf(__cosf(my_relt * twv[kt * 8 + j] + tbv[kt * 8 + j]));
      afrag[kt] = a;
    }
    const float* mr = msg + (size_t)(e0 + r) * 64;   // streaming, coalesced
#pragma unroll
    for (int kt = 2; kt < 4; ++kt) {
      int base = (kt - 2) * 32 + k4;
      float4 lo = rvalid ? *(const float4*)(mr + base) : make_float4(0, 0, 0, 0);
      float4 hi = rvalid ? *(const float4*)(mr + base + 16) : make_float4(0, 0, 0, 0);
      bf16x8 a;
      a[0] = f2bf(lo.x); a[1] = f2bf(lo.y); a[2] = f2bf(lo.z); a[3] = f2bf(lo.w);
      a[4] = f2bf(hi.x); a[5] = f2bf(hi.y); a[6] = f2bf(hi.z); a[7] = f2bf(hi.w);
      afrag[kt] = a;
    }

#pragma unroll
    for (int nt = 0; nt < 8; ++nt) {
      bf16x8 bfrag[4];
#pragma unroll
      for (int kt = 0; kt < 4; ++kt)
        *(uint4*)&bfrag[kt] = wlds[(nt * 4 + kt) * 64 + lane];
      f32x4 acc = {0.f, 0.f, 0.f, 0.f};
#pragma unroll
      for (int kt = 0; kt < 4; ++kt)
        acc = __builtin_amdgcn_mfma_f32_16x16x32_bf16(afrag[kt], bfrag[kt], acc, 0, 0, 0);
      int col = nt * 16 + (lane & 15);
#pragma unroll
      for (int reg = 0; reg < 4; ++reg) {
        int rr = (lane >> 4) * 4 + reg;
        int wb = (rr * 256 + col * 2) ^ (((rr >> 2) & 3) << 5);  // swizzled
        *(short*)(myl + wb) = f2bf(acc[reg]);
      }
    }
#pragma unroll
    for (int i = 0; i < 8; ++i) {
      int rr = i * 2 + (lane >> 5);
      int er = e0 + rr;
      int drow = __shfl(rank16, rr);        // sorted row for this edge
      int rb = (rr * 256 + (lane & 31) * 8) ^ (((rr >> 2) & 3) << 5);
      uint2 val = *(const uint2*)(myl + rb);
      if (er < E)
        *(uint2*)(e_s + (size_t)drow * 128 + (lane & 31) * 4) = val;
    }
  }
}

// ---- per-dst aggregation: pure-store out = skip(bf16) + attn --------------
// lane owns channel pair c2=2*lane -> head h=lane>>3. e_s padded by 64 rows
// (affine loads); vo keeps clamped LDS broadcast; shift-free softmax.
__global__ __launch_bounds__(256) void k_agg(
    const int* __restrict__ offs, const int* __restrict__ src_s,
    const short* __restrict__ e_s, const short* __restrict__ qb,
    const short* __restrict__ kb, const short* __restrict__ vb,
    const short* __restrict__ skipb, float* __restrict__ out, int N) {
  __shared__ int lds_vo[4][64];
  const int wave = threadIdx.x >> 6;
  const int lane = threadIdx.x & 63;
  const int n0 = (blockIdx.x * 4 + wave) * 2;
  if (n0 >= N) return;
  const int c2 = lane * 2;
  const bool hasB = (n0 + 1) < N;

  // hoisted setup loads for both nodes (independent -> issue together)
  const int offA = offs[n0];
  const int endA = offs[n0 + 1];
  const int endB = hasB ? offs[n0 + 2] : endA;
  const int offB = endA;
  unsigned qvA = *(const unsigned*)(qb + (size_t)n0 * 128 + c2);
  unsigned qvB = hasB ? *(const unsigned*)(qb + (size_t)(n0 + 1) * 128 + c2) : 0u;
  unsigned svA = *(const unsigned*)(skipb + (size_t)n0 * 128 + c2);
  unsigned svB = hasB ? *(const unsigned*)(skipb + (size_t)(n0 + 1) * 128 + c2) : 0u;

  auto process = [&](int off, int end, unsigned qv, float2& attn) {
    attn = make_float2(0.f, 0.f);
    if (end <= off) return;
    const float q0 = bflo(qv) * 0.25f;    // fold /sqrt(HEAD_DIM) into q
    const float q1 = bfhi(qv) * 0.25f;
    float s = 0.f, acc0 = 0.f, acc1 = 0.f;
    for (int c0 = off; c0 < end; c0 += 64) {
      const int cnt = min(64, end - c0);
      if (lane < cnt) lds_vo[wave][lane] = src_s[c0 + lane] * 128;
      const int lim = cnt - 1;
      for (int g0 = 0; g0 < cnt; g0 += 8) {
        const short* ebase = e_s + (size_t)(c0 + g0) * 128 + c2;
        unsigned evr[8], kvr[8], vvr[8];
#pragma unroll
        for (int g = 0; g < 8; ++g) {
          int jj = g0 + g;
          jj = (jj > lim) ? lim : jj;     // clamp for k/v only
          int vo = lds_vo[wave][jj];
          evr[g] = *(const unsigned*)(ebase + g * 128);   // affine (padded)
          kvr[g] = *(const unsigned*)(kb + vo + c2);
          vvr[g] = *(const unsigned*)(vb + vo + c2);
        }
#pragma unroll
        for (int g = 0; g < 8; ++g) {
          float part = q0 * (bflo(kvr[g]) + bflo(evr[g]))
                     + q1 * (bfhi(kvr[g]) + bfhi(evr[g]));
          part += __shfl_xor(part, 1);
          part += __shfl_xor(part, 2);
          part += __shfl_xor(part, 4);    // sum over the 8-lane head group
          float p = (g0 + g <= lim) ? __expf(part) : 0.f;
          s += p;
          acc0 = fmaf(p, bflo(vvr[g]) + bflo(evr[g]), acc0);
          acc1 = fmaf(p, bfhi(vvr[g]) + bfhi(evr[g]), acc1);
        }
      }
    }
    float r = 1.f / (s + 1e-16f);
    attn.x = acc0 * r;
    attn.y = acc1 * r;
  };

  float2 aA, aB;
  process(offA, endA, qvA, aA);
  *(float2*)(out + (size_t)n0 * 128 + c2) =
      make_float2(bflo(svA) + aA.x, bfhi(svA) + aA.y);
  if (hasB) {
    process(offB, endB, qvB, aB);
    *(float2*)(out + (size_t)(n0 + 1) * 128 + c2) =
        make_float2(bflo(svB) + aB.x, bfhi(svB) + aB.y);
  }
}

extern "C" void kernel_launch(void* const* d_in, const int* in_sizes, int n_in,
                              void* d_out, int out_size, void* d_ws, size_t ws_size,
                              hipStream_t stream) {
  const float* feats = (const float*)d_in[0];
  const float* x     = (const float*)d_in[1];
  const float* lu    = (const float*)d_in[2];
  const int*   ei    = (const int*)d_in[3];
  const float* t     = (const float*)d_in[4];
  const float* msg   = (const float*)d_in[5];
  const float* tw    = (const float*)d_in[6];
  const float* tb    = (const float*)d_in[7];
  const float* Wq    = (const float*)d_in[8];
  const float* bq    = (const float*)d_in[9];
  const float* Wk    = (const float*)d_in[10];
  const float* bk    = (const float*)d_in[11];
  const float* Wv    = (const float*)d_in[12];
  const float* bv    = (const float*)d_in[13];
  const float* We    = (const float*)d_in[14];
  const float* Wskip = (const float*)d_in[15];
  const float* bskip = (const float*)d_in[16];
  float* out = (float*)d_out;
  const int N = in_sizes[2];
  const int E = in_sizes[4];

  char* ws = (char*)d_ws;
  short* wfrag = (short*)ws; ws += 5 * 2048 * 16;            // 160 KB
  short* qb    = (short*)ws; ws += (size_t)N * 128 * 2;
  short* kbuf  = (short*)ws; ws += (size_t)N * 128 * 2;
  short* vbuf  = (short*)ws; ws += (size_t)N * 128 * 2;
  short* skipb = (short*)ws; ws += (size_t)N * 128 * 2;
  short* e_s   = (short*)ws; ws += (size_t)(E + 64) * 128 * 2;  // +64 pad rows
  int* counts  = (int*)ws;   ws += (size_t)(N + 1) * 4;
  int* offs    = (int*)ws;   ws += (size_t)(N + 4) * 4;
  int* cursor  = (int*)ws;   ws += (size_t)N * 4;
  int* rank    = (int*)ws;   ws += (size_t)E * 4;
  int* src_s   = (int*)ws;   ws += (size_t)E * 4;

  const int nb = (N + 1023) / 1024;
  const int nhist = (E + 255) / 256;
  const int nnode = 512;

  hipMemsetAsync(counts, 0, (size_t)(N + 1) * 4, stream);

  PrepArgs pa;
  pa.W[0] = Wq; pa.W[1] = Wk; pa.W[2] = Wv; pa.W[3] = Wskip; pa.W[4] = We;
  k_front<<<40 + nhist, 256, 0, stream>>>(pa, wfrag, ei, counts, E);

  k_scan2<<<nb, 1024, 0, stream>>>(counts, offs, cursor, N);

  NodeArgs na;
  na.wf = wfrag;
  na.bias[0] = bq; na.bias[1] = bk; na.bias[2] = bv; na.bias[3] = bskip;
  na.outp[0] = qb; na.outp[1] = kbuf; na.outp[2] = vbuf; na.outp[3] = skipb;
  k_nodescat<<<nnode + nhist, 256, 0, stream>>>(x, feats, na, N, ei, cursor,
                                                rank, src_s, E, nnode);

  k_egemm<<<512, 512, 0, stream>>>(lu, ei, t, msg, tw, tb, wfrag,
                                   rank, e_s, E);
  k_agg<<<(N + 7) / 8, 256, 0, stream>>>(offs, src_s, e_s, qb, kbuf, vbuf,
                                         skipb, out, N);
}